// Round 16
// baseline (312.158 us; speedup 1.0000x reference)
//
#include <hip/hip_runtime.h>
#include <hip/hip_bf16.h>

// GCN 2-layer forward on MI355X — round 16 = round-11 base (best, 286us;
// EPB back to 8192) + wave-per-row gemm1 retry with the r7 failure ROOT-CAUSED:
// __launch_bounds__(256) w/o min-waves let the compiler target ~88 VGPR and
// demote the 128-VGPR W1 fragment to LDS scratch (16KB, 25M bank conflicts).
// Fix: __launch_bounds__(256,2) (VGPR budget 256) + named float4 registers.
// gemm1 now writes bf16 hs directly (dinv folded) — part/combine deleted.
// Inputs: x[N,512] f32, edge_index[2,E] int32, edge_weight[E] f32,
//         W1[512,16], b1[16], W2[16,10], b2[10]
// Outputs (concat): log_softmax(logits)[N,10], x1[N,16]

#define NF1 16   // hidden
#define NF2 10   // classes
#define FIN 512
#define EPB 8192 // edges per coarse block (256 thr * 32)

typedef unsigned long long ull;
typedef unsigned short us;

// bf16 pack/unpack (round-to-nearest-even; data has no NaN)
__device__ __forceinline__ us f2bf(float f) {
    union { float f; unsigned u; } v; v.f = f;
    unsigned r = v.u + 0x7FFFu + ((v.u >> 16) & 1u);
    return (us)(r >> 16);
}
__device__ __forceinline__ float bf2f(us h) {
    union { unsigned u; float f; } v; v.u = ((unsigned)h) << 16;
    return v.f;
}

// ---------- A: coarse count (col>>9) into per-block histograms ----------
__global__ __launch_bounds__(256) void coarse_count_kernel(const int* __restrict__ col,
                                                           int* __restrict__ blkhist,
                                                           int E, int NB, int NBLK) {
    __shared__ int lh[256];
    int t = threadIdx.x;
    lh[t] = 0;
    __syncthreads();
    int base = blockIdx.x * EPB;
    int cnt = min(EPB, E - base);
    for (int i = t; i < cnt; i += 256)
        atomicAdd(&lh[col[base + i] >> 9], 1);
    __syncthreads();
    if (t < NB) blkhist[t * NBLK + blockIdx.x] = lh[t];
}

// ---------- B1: per-bucket exclusive scan over blocks (parallel) ----------
__global__ __launch_bounds__(512) void bucket_scan_kernel(int* __restrict__ blkhist,
                                                          int* __restrict__ btot,
                                                          int NBLK) {
    __shared__ int s[512];
    int t = threadIdx.x;
    int* p = blkhist + (size_t)blockIdx.x * NBLK;
    int carry = 0;
    for (int base = 0; base < NBLK; base += 512) {
        int idx = base + t;
        int v = (idx < NBLK) ? p[idx] : 0;
        s[t] = v;
        __syncthreads();
        for (int off = 1; off < 512; off <<= 1) {
            int u = (t >= off) ? s[t - off] : 0;
            __syncthreads();
            s[t] += u;
            __syncthreads();
        }
        if (idx < NBLK) p[idx] = s[t] - v + carry;
        carry += s[511];
        __syncthreads();
    }
    if (t == 0) btot[blockIdx.x] = carry;
}

// ---------- B2: scan bucket totals -> bbase ----------
__global__ __launch_bounds__(256) void base_scan_kernel(const int* __restrict__ btot,
                                                        int* __restrict__ bbase,
                                                        int* __restrict__ rowptr,
                                                        int NB, int E, int N) {
    __shared__ int s[256];
    int t = threadIdx.x;
    int v = (t < NB) ? btot[t] : 0;
    s[t] = v;
    __syncthreads();
    for (int off = 1; off < 256; off <<= 1) {
        int u = (t >= off) ? s[t - off] : 0;
        __syncthreads();
        s[t] += u;
        __syncthreads();
    }
    if (t < NB) bbase[t] = s[t] - v;
    if (t == 0) { bbase[NB] = E; rowptr[N] = E; }
}

// ---------- C: coarse scatter into bucket-ordered pool ----------
// pool entry: hi32 = (c9<<20)|row, lo32 = weight bits
__global__ __launch_bounds__(256) void coarse_scatter_kernel(const int* __restrict__ row,
                                                             const int* __restrict__ col,
                                                             const float* __restrict__ ew,
                                                             const int* __restrict__ blkhist,
                                                             const int* __restrict__ bbase,
                                                             ull* __restrict__ pool,
                                                             int E, int NB, int NBLK) {
    __shared__ int cur[256];
    int t = threadIdx.x;
    if (t < NB) cur[t] = blkhist[t * NBLK + blockIdx.x] + bbase[t];
    __syncthreads();
    int base = blockIdx.x * EPB;
    int cnt = min(EPB, E - base);
    for (int i = t; i < cnt; i += 256) {
        int e = base + i;
        int c = col[e], r = row[e];
        float w = ew[e];
        int b = c >> 9, c9 = c & 511;
        int pos = atomicAdd(&cur[b], 1);
        pool[pos] = ((ull)((((unsigned)c9) << 20) | (unsigned)r) << 32) | (ull)__float_as_uint(w);
    }
}

// ---------- D: fine sort within bucket (512 cols) -> CSR (raw w), rowptr, dinv ----------
__global__ __launch_bounds__(1024) void fine_sort_kernel(const ull* __restrict__ pool,
                                                         const int* __restrict__ bbase,
                                                         ull* __restrict__ csr,
                                                         int* __restrict__ rowptr,
                                                         float* __restrict__ dinv, int N) {
    __shared__ int hist[512];
    __shared__ float wsum[512];
    __shared__ int cur[512];
    int t = threadIdx.x;
    int b = blockIdx.x;
    int bb = bbase[b], be = bbase[b + 1];
    int Ki = be - bb;
    if (t < 512) { hist[t] = 0; wsum[t] = 0.0f; }
    __syncthreads();
    for (int i = t; i < Ki; i += 1024) {
        ull p = pool[bb + i];
        unsigned hi = (unsigned)(p >> 32);
        int c9 = (hi >> 20) & 511;
        atomicAdd(&hist[c9], 1);
        atomicAdd(&wsum[c9], __uint_as_float((unsigned)p));
    }
    __syncthreads();
    int own = (t < 512) ? hist[t] : 0;
    if (t < 512) cur[t] = own;
    __syncthreads();
    for (int off = 1; off < 512; off <<= 1) {
        int v = (t >= off && t < 512) ? cur[t - off] : 0;
        __syncthreads();
        if (t < 512) cur[t] += v;
        __syncthreads();
    }
    int excl = (t < 512) ? (cur[t] - own) : 0;
    if (t < 512) cur[t] = excl;
    int c = (b << 9) + t;
    if (t < 512 && c < N) {
        rowptr[c] = bb + excl;
        dinv[c] = rsqrtf(1.0f + wsum[t]);       // deg = self(1) + sum(w)
    }
    __syncthreads();
    for (int i = t; i < Ki; i += 1024) {
        ull p = pool[bb + i];
        unsigned hi = (unsigned)(p >> 32);
        int c9 = (hi >> 20) & 511;
        unsigned r = hi & 0xFFFFFu;
        int k = atomicAdd(&cur[c9], 1);
        csr[bb + k] = ((p & 0xFFFFFFFFull) << 32) | (ull)r;   // raw weight
    }
}

// ---------- GEMM1: hs16 = bf16(dinv .* (x @ W1)), one WAVE per row ----------
// Lane l owns k in {4l..4l+3} u {256+4l..+3}: every x wave-load is 1KiB
// contiguous (16 cache lines/instruction — the full-BW pattern). W1 fragment
// (8 rows x 16 = 32 float4) lives in NAMED registers; __launch_bounds__(256,2)
// gives the 256-VGPR budget that r7 lacked (it demoted to LDS at default
// occupancy). Butterfly reduce (r7-verified semantics); lane<16 stores bf16.
#define FMA16(s, p0, p1, p2, p3)                                    \
    a0.x = fmaf(s, p0.x, a0.x); a0.y = fmaf(s, p0.y, a0.y);         \
    a0.z = fmaf(s, p0.z, a0.z); a0.w = fmaf(s, p0.w, a0.w);         \
    a1.x = fmaf(s, p1.x, a1.x); a1.y = fmaf(s, p1.y, a1.y);         \
    a1.z = fmaf(s, p1.z, a1.z); a1.w = fmaf(s, p1.w, a1.w);         \
    a2.x = fmaf(s, p2.x, a2.x); a2.y = fmaf(s, p2.y, a2.y);         \
    a2.z = fmaf(s, p2.z, a2.z); a2.w = fmaf(s, p2.w, a2.w);         \
    a3.x = fmaf(s, p3.x, a3.x); a3.y = fmaf(s, p3.y, a3.y);         \
    a3.z = fmaf(s, p3.z, a3.z); a3.w = fmaf(s, p3.w, a3.w);

__global__ __launch_bounds__(256, 2) void gemm1_kernel(const float* __restrict__ x,
                                                       const float* __restrict__ W1,
                                                       const float* __restrict__ dinv,
                                                       us* __restrict__ hs16,
                                                       int N, int totalWaves) {
    int wave = (blockIdx.x * 256 + threadIdx.x) >> 6;
    int lane = threadIdx.x & 63;

    const float4* Wv = reinterpret_cast<const float4*>(W1);  // row r = Wv[4r..4r+3]
    int ra = 4 * lane;           // chunk-a rows ra..ra+3
    int rb = 256 + 4 * lane;     // chunk-b rows

    float4 wa00 = Wv[4 * (ra + 0) + 0], wa01 = Wv[4 * (ra + 0) + 1], wa02 = Wv[4 * (ra + 0) + 2], wa03 = Wv[4 * (ra + 0) + 3];
    float4 wa10 = Wv[4 * (ra + 1) + 0], wa11 = Wv[4 * (ra + 1) + 1], wa12 = Wv[4 * (ra + 1) + 2], wa13 = Wv[4 * (ra + 1) + 3];
    float4 wa20 = Wv[4 * (ra + 2) + 0], wa21 = Wv[4 * (ra + 2) + 1], wa22 = Wv[4 * (ra + 2) + 2], wa23 = Wv[4 * (ra + 2) + 3];
    float4 wa30 = Wv[4 * (ra + 3) + 0], wa31 = Wv[4 * (ra + 3) + 1], wa32 = Wv[4 * (ra + 3) + 2], wa33 = Wv[4 * (ra + 3) + 3];
    float4 wb00 = Wv[4 * (rb + 0) + 0], wb01 = Wv[4 * (rb + 0) + 1], wb02 = Wv[4 * (rb + 0) + 2], wb03 = Wv[4 * (rb + 0) + 3];
    float4 wb10 = Wv[4 * (rb + 1) + 0], wb11 = Wv[4 * (rb + 1) + 1], wb12 = Wv[4 * (rb + 1) + 2], wb13 = Wv[4 * (rb + 1) + 3];
    float4 wb20 = Wv[4 * (rb + 2) + 0], wb21 = Wv[4 * (rb + 2) + 1], wb22 = Wv[4 * (rb + 2) + 2], wb23 = Wv[4 * (rb + 2) + 3];
    float4 wb30 = Wv[4 * (rb + 3) + 0], wb31 = Wv[4 * (rb + 3) + 1], wb32 = Wv[4 * (rb + 3) + 2], wb33 = Wv[4 * (rb + 3) + 3];

    int row = wave;
    if (row >= N) return;
    float4 xa = *reinterpret_cast<const float4*>(&x[(size_t)row * FIN + 4 * lane]);
    float4 xb = *reinterpret_cast<const float4*>(&x[(size_t)row * FIN + 256 + 4 * lane]);

    for (; row < N; row += totalWaves) {
        int nrow = row + totalWaves;
        float4 xa_n = make_float4(0.f, 0.f, 0.f, 0.f);
        float4 xb_n = xa_n;
        if (nrow < N) {   // prefetch next row; stays in flight under the FMAs
            xa_n = *reinterpret_cast<const float4*>(&x[(size_t)nrow * FIN + 4 * lane]);
            xb_n = *reinterpret_cast<const float4*>(&x[(size_t)nrow * FIN + 256 + 4 * lane]);
        }

        float4 a0 = make_float4(0.f, 0.f, 0.f, 0.f), a1 = a0, a2 = a0, a3 = a0;
        FMA16(xa.x, wa00, wa01, wa02, wa03)
        FMA16(xa.y, wa10, wa11, wa12, wa13)
        FMA16(xa.z, wa20, wa21, wa22, wa23)
        FMA16(xa.w, wa30, wa31, wa32, wa33)
        FMA16(xb.x, wb00, wb01, wb02, wb03)
        FMA16(xb.y, wb10, wb11, wb12, wb13)
        FMA16(xb.z, wb20, wb21, wb22, wb23)
        FMA16(xb.w, wb30, wb31, wb32, wb33)

        // butterfly reduce, r7-verified semantics: acc[0..15] = (a0,a1,a2,a3)
        {   // xor 1: fold 16 -> 8
            bool up = (lane & 1);
            float4 t0 = up ? a0 : a2, t1 = up ? a1 : a3;
            float4 k0 = up ? a2 : a0, k1 = up ? a3 : a1;
            t0.x = __shfl_xor(t0.x, 1); t0.y = __shfl_xor(t0.y, 1);
            t0.z = __shfl_xor(t0.z, 1); t0.w = __shfl_xor(t0.w, 1);
            t1.x = __shfl_xor(t1.x, 1); t1.y = __shfl_xor(t1.y, 1);
            t1.z = __shfl_xor(t1.z, 1); t1.w = __shfl_xor(t1.w, 1);
            a0.x = k0.x + t0.x; a0.y = k0.y + t0.y; a0.z = k0.z + t0.z; a0.w = k0.w + t0.w;
            a1.x = k1.x + t1.x; a1.y = k1.y + t1.y; a1.z = k1.z + t1.z; a1.w = k1.w + t1.w;
        }
        {   // xor 2: fold 8 -> 4
            bool up = (lane & 2);
            float4 t = up ? a0 : a1;
            float4 k = up ? a1 : a0;
            t.x = __shfl_xor(t.x, 2); t.y = __shfl_xor(t.y, 2);
            t.z = __shfl_xor(t.z, 2); t.w = __shfl_xor(t.w, 2);
            a0.x = k.x + t.x; a0.y = k.y + t.y; a0.z = k.z + t.z; a0.w = k.w + t.w;
        }
        {   // xor 4: fold 4 -> 2
            bool up = (lane & 4);
            float tx = up ? a0.x : a0.z, ty = up ? a0.y : a0.w;
            float kx = up ? a0.z : a0.x, ky = up ? a0.w : a0.y;
            tx = __shfl_xor(tx, 4); ty = __shfl_xor(ty, 4);
            a0.x = kx + tx; a0.y = ky + ty;
        }
        {   // xor 8: fold 2 -> 1
            bool up = (lane & 8);
            float t = up ? a0.x : a0.y;
            float k = up ? a0.y : a0.x;
            t = __shfl_xor(t, 8);
            a0.x = k + t;
        }
        a0.x += __shfl_xor(a0.x, 16);
        a0.x += __shfl_xor(a0.x, 32);

        if (lane < 16) {
            int f = ((lane & 1) << 3) | ((lane & 2) << 1) | ((lane & 4) >> 1) | ((lane & 8) >> 3);
            hs16[(size_t)row * NF1 + f] = f2bf(dinv[row] * a0.x);
        }
        xa = xa_n;
        xb = xb_n;
    }
}

// ---------- gather layer 1: x1[c] = b1 + di*( sum ew_i*hs[r_i] + hs[c] ) ----------
__global__ __launch_bounds__(256) void gather1_kernel(const ull* __restrict__ csr,
                                                      const int* __restrict__ rowptr,
                                                      const float* __restrict__ dinv,
                                                      const us* __restrict__ hs16,
                                                      const float* __restrict__ b1,
                                                      float* __restrict__ x1, int N) {
    int t = blockIdx.x * 256 + threadIdx.x;
    int node = t >> 4, f = t & 15;
    if (node >= N) return;
    int s = rowptr[node], e = rowptr[node + 1];
    float di = dinv[node];
    float acc = bf2f(hs16[(size_t)node * NF1 + f]);   // self-loop: hs[c]
    int i = s;
    for (; i + 1 < e; i += 2) {
        ull v0 = csr[i], v1 = csr[i + 1];
        int r0 = (int)(v0 & 0xffffffffull); float w0 = __uint_as_float((unsigned)(v0 >> 32));
        int r1 = (int)(v1 & 0xffffffffull); float w1 = __uint_as_float((unsigned)(v1 >> 32));
        acc += w0 * bf2f(hs16[(size_t)r0 * NF1 + f]);
        acc += w1 * bf2f(hs16[(size_t)r1 * NF1 + f]);
    }
    if (i < e) {
        ull v = csr[i];
        int r = (int)(v & 0xffffffffull); float w = __uint_as_float((unsigned)(v >> 32));
        acc += w * bf2f(hs16[(size_t)r * NF1 + f]);
    }
    x1[(size_t)node * NF1 + f] = b1[f] + di * acc;
}

// ---------- GEMM2: hh16 = bf16( dinv[j] * (relu(x1[j]) @ W2) ) ----------
__global__ __launch_bounds__(256) void gemm2_kernel(const float* __restrict__ x1,
                                                    const float* __restrict__ W2,
                                                    const float* __restrict__ dinv,
                                                    us* __restrict__ hh16, int N) {
    int j = blockIdx.x * 256 + threadIdx.x;
    if (j >= N) return;
    float xr[NF1];
#pragma unroll
    for (int f = 0; f < NF1; f++) xr[f] = fmaxf(x1[(size_t)j * NF1 + f], 0.0f);
    float d = dinv[j];
    float o[NF2];
#pragma unroll
    for (int c = 0; c < NF2; c++) {
        float acc = 0.0f;
#pragma unroll
        for (int f = 0; f < NF1; f++) acc += xr[f] * W2[f * NF2 + c];
        o[c] = d * acc;
    }
    // pack 10 bf16 as 5 uints (row offset j*20 B is 4B-aligned)
    unsigned* hp = reinterpret_cast<unsigned*>(const_cast<us*>(hh16) + (size_t)j * NF2);
#pragma unroll
    for (int cp = 0; cp < 5; cp++)
        hp[cp] = (unsigned)f2bf(o[2 * cp]) | ((unsigned)f2bf(o[2 * cp + 1]) << 16);
}

// ---------- gather layer 2 + fused log-softmax ----------
__global__ __launch_bounds__(256) void gather2_lsm_kernel(const ull* __restrict__ csr,
                                                          const int* __restrict__ rowptr,
                                                          const float* __restrict__ dinv,
                                                          const us* __restrict__ hh16,
                                                          const float* __restrict__ b2,
                                                          float* __restrict__ out, int N) {
    int t = blockIdx.x * 256 + threadIdx.x;
    int node = t >> 4, f = t & 15;
    bool act = (node < N) && (f < NF2);
    float acc = 0.0f;
    if (node < N) {
        int s = rowptr[node], e = rowptr[node + 1];
        float di = dinv[node];
        acc = act ? bf2f(hh16[(size_t)node * NF2 + f]) : 0.0f;   // self-loop
        int i = s;
        for (; i + 1 < e; i += 2) {
            ull v0 = csr[i], v1 = csr[i + 1];
            int r0 = (int)(v0 & 0xffffffffull); float w0 = __uint_as_float((unsigned)(v0 >> 32));
            int r1 = (int)(v1 & 0xffffffffull); float w1 = __uint_as_float((unsigned)(v1 >> 32));
            float h0 = (f < NF2) ? bf2f(hh16[(size_t)r0 * NF2 + f]) : 0.0f;
            float h1 = (f < NF2) ? bf2f(hh16[(size_t)r1 * NF2 + f]) : 0.0f;
            acc += w0 * h0 + w1 * h1;
        }
        if (i < e) {
            ull v = csr[i];
            int r = (int)(v & 0xffffffffull); float w = __uint_as_float((unsigned)(v >> 32));
            float hv = (f < NF2) ? bf2f(hh16[(size_t)r * NF2 + f]) : 0.0f;
            acc += w * hv;
        }
        acc = b2[f] + di * acc;
    }
    // log-softmax across the 16-lane group (10 active lanes)
    float m = act ? acc : -INFINITY;
#pragma unroll
    for (int off = 1; off < 16; off <<= 1) m = fmaxf(m, __shfl_xor(m, off, 16));
    float p = act ? expf(acc - m) : 0.0f;
    float ssum = p;
#pragma unroll
    for (int off = 1; off < 16; off <<= 1) ssum += __shfl_xor(ssum, off, 16);
    if (act) out[(size_t)node * NF2 + f] = acc - m - logf(ssum);
}

extern "C" void kernel_launch(void* const* d_in, const int* in_sizes, int n_in,
                              void* d_out, int out_size, void* d_ws, size_t ws_size,
                              hipStream_t stream) {
    const float* x  = (const float*)d_in[0];
    const int*   ei = (const int*)d_in[1];
    const float* ew = (const float*)d_in[2];
    const float* W1 = (const float*)d_in[3];
    const float* b1 = (const float*)d_in[4];
    const float* W2 = (const float*)d_in[5];
    const float* b2 = (const float*)d_in[6];

    const int E = in_sizes[2];           // 3,200,000
    const int N = in_sizes[0] / FIN;     // 100,000
    const int* row = ei;
    const int* col = ei + E;

    const int NB   = (N + 511) >> 9;     // coarse buckets (196)
    const int NBLK = (E + EPB - 1) / EPB;

    float* out    = (float*)d_out;
    float* logits = out;                        // [N,10]
    float* x1     = out + (size_t)N * NF2;      // [N,16]

    char* ws = (char*)d_ws;
    size_t off = 0;
    auto alloc = [&](size_t bytes) { void* p = ws + off; off += (bytes + 255) / 256 * 256; return p; };
    ull*   pool    = (ull*)  alloc((size_t)E * 8);
    ull*   csr     = (ull*)  alloc((size_t)E * 8);
    us*    hs16    = (us*)   alloc((size_t)N * NF1 * 2);       // bf16 dinv*(x@W1)
    us*    hh16    = (us*)   alloc((size_t)N * NF2 * 2 + 64);  // bf16 dinv*relu(x1)@W2
    float* dinv    = (float*)alloc((size_t)N * 4);
    int*   rowptr  = (int*)  alloc((size_t)(N + 1) * 4);
    int*   blkhist = (int*)  alloc((size_t)NB * NBLK * 4);
    int*   btot    = (int*)  alloc((size_t)NB * 4);
    int*   bbase   = (int*)  alloc((size_t)(NB + 1) * 4);
    (void)ws_size; (void)n_in; (void)out_size;

    dim3 blk(256);
    int gN  = (N + 255) / 256;
    int g16 = (N + 15) / 16;

    // build CSR (no global atomics)
    coarse_count_kernel<<<NBLK, blk, 0, stream>>>(col, blkhist, E, NB, NBLK);
    bucket_scan_kernel<<<NB, dim3(512), 0, stream>>>(blkhist, btot, NBLK);
    base_scan_kernel<<<1, blk, 0, stream>>>(btot, bbase, rowptr, NB, E, N);
    coarse_scatter_kernel<<<NBLK, blk, 0, stream>>>(row, col, ew, blkhist, bbase, pool, E, NB, NBLK);
    fine_sort_kernel<<<NB, dim3(1024), 0, stream>>>(pool, bbase, csr, rowptr, dinv, N);

    // layer 1: wave-per-row gemm1 writes bf16 hs directly (no part/combine)
    const int gemmBlocks = 1024;             // 4096 waves, 2 blocks/CU resident
    const int totalWaves = gemmBlocks * 4;
    gemm1_kernel<<<gemmBlocks, blk, 0, stream>>>(x, W1, dinv, hs16, N, totalWaves);
    gather1_kernel<<<g16, blk, 0, stream>>>(csr, rowptr, dinv, hs16, b1, x1, N);

    // layer 2
    gemm2_kernel<<<gN, blk, 0, stream>>>(x1, W2, dinv, hh16, N);
    gather2_lsm_kernel<<<g16, blk, 0, stream>>>(csr, rowptr, dinv, hh16, b2, logits, N);
}

// Round 17
// 268.279 us; speedup vs baseline: 1.1636x; 1.1636x over previous
//
#include <hip/hip_runtime.h>
#include <hip/hip_bf16.h>

// GCN 2-layer forward on MI355X — round 17 = round-11 EXACTLY (best, 286us;
// rounds 12-16 experiments all regressed and are reverted) + ONE change:
// CSR entries compressed 8B -> 4B: weight is positive, stored as 15-bit
// float (8exp+7man, RNE), row in 17 bits (N<2^17). Entry=(w15<<17)|r.
// Halves csr write + both gather streaming reads (-38.4 MB).
// Inputs: x[N,512] f32, edge_index[2,E] int32, edge_weight[E] f32,
//         W1[512,16], b1[16], W2[16,10], b2[10]
// Outputs (concat): log_softmax(logits)[N,10], x1[N,16]

#define NF1 16   // hidden
#define NF2 10   // classes
#define FIN 512
#define EPB 8192 // edges per coarse block (256 thr * 32)
#define SK  4    // gemm1 split-K factor

typedef unsigned long long ull;
typedef unsigned short us;

// bf16 pack/unpack (round-to-nearest-even; data has no NaN)
__device__ __forceinline__ us f2bf(float f) {
    union { float f; unsigned u; } v; v.f = f;
    unsigned r = v.u + 0x7FFFu + ((v.u >> 16) & 1u);
    return (us)(r >> 16);
}
__device__ __forceinline__ float bf2f(us h) {
    union { unsigned u; float f; } v; v.u = ((unsigned)h) << 16;
    return v.f;
}
// 15-bit positive-float weight decode: bits[30:16] stored, sign=0
__device__ __forceinline__ float w15f(unsigned e) {
    union { unsigned u; float f; } v; v.u = (e >> 17) << 16;
    return v.f;
}

// ---------- A: coarse count (col>>9) into per-block histograms ----------
__global__ __launch_bounds__(256) void coarse_count_kernel(const int* __restrict__ col,
                                                           int* __restrict__ blkhist,
                                                           int E, int NB, int NBLK) {
    __shared__ int lh[256];
    int t = threadIdx.x;
    lh[t] = 0;
    __syncthreads();
    int base = blockIdx.x * EPB;
    int cnt = min(EPB, E - base);
    for (int i = t; i < cnt; i += 256)
        atomicAdd(&lh[col[base + i] >> 9], 1);
    __syncthreads();
    if (t < NB) blkhist[t * NBLK + blockIdx.x] = lh[t];
}

// ---------- B1: per-bucket exclusive scan over blocks (parallel) ----------
__global__ __launch_bounds__(512) void bucket_scan_kernel(int* __restrict__ blkhist,
                                                          int* __restrict__ btot,
                                                          int NBLK) {
    __shared__ int s[512];
    int t = threadIdx.x;
    int* p = blkhist + (size_t)blockIdx.x * NBLK;
    int carry = 0;
    for (int base = 0; base < NBLK; base += 512) {
        int idx = base + t;
        int v = (idx < NBLK) ? p[idx] : 0;
        s[t] = v;
        __syncthreads();
        for (int off = 1; off < 512; off <<= 1) {
            int u = (t >= off) ? s[t - off] : 0;
            __syncthreads();
            s[t] += u;
            __syncthreads();
        }
        if (idx < NBLK) p[idx] = s[t] - v + carry;
        carry += s[511];
        __syncthreads();
    }
    if (t == 0) btot[blockIdx.x] = carry;
}

// ---------- B2: scan bucket totals -> bbase ----------
__global__ __launch_bounds__(256) void base_scan_kernel(const int* __restrict__ btot,
                                                        int* __restrict__ bbase,
                                                        int* __restrict__ rowptr,
                                                        int NB, int E, int N) {
    __shared__ int s[256];
    int t = threadIdx.x;
    int v = (t < NB) ? btot[t] : 0;
    s[t] = v;
    __syncthreads();
    for (int off = 1; off < 256; off <<= 1) {
        int u = (t >= off) ? s[t - off] : 0;
        __syncthreads();
        s[t] += u;
        __syncthreads();
    }
    if (t < NB) bbase[t] = s[t] - v;
    if (t == 0) { bbase[NB] = E; rowptr[N] = E; }
}

// ---------- C: coarse scatter into bucket-ordered pool ----------
// pool entry: hi32 = (c9<<20)|row, lo32 = weight bits (f32)
__global__ __launch_bounds__(256) void coarse_scatter_kernel(const int* __restrict__ row,
                                                             const int* __restrict__ col,
                                                             const float* __restrict__ ew,
                                                             const int* __restrict__ blkhist,
                                                             const int* __restrict__ bbase,
                                                             ull* __restrict__ pool,
                                                             int E, int NB, int NBLK) {
    __shared__ int cur[256];
    int t = threadIdx.x;
    if (t < NB) cur[t] = blkhist[t * NBLK + blockIdx.x] + bbase[t];
    __syncthreads();
    int base = blockIdx.x * EPB;
    int cnt = min(EPB, E - base);
    for (int i = t; i < cnt; i += 256) {
        int e = base + i;
        int c = col[e], r = row[e];
        float w = ew[e];
        int b = c >> 9, c9 = c & 511;
        int pos = atomicAdd(&cur[b], 1);
        pool[pos] = ((ull)((((unsigned)c9) << 20) | (unsigned)r) << 32) | (ull)__float_as_uint(w);
    }
}

// ---------- D: fine sort within bucket -> compressed CSR, rowptr, dinv ----------
__global__ __launch_bounds__(1024) void fine_sort_kernel(const ull* __restrict__ pool,
                                                         const int* __restrict__ bbase,
                                                         unsigned* __restrict__ csr,
                                                         int* __restrict__ rowptr,
                                                         float* __restrict__ dinv, int N) {
    __shared__ int hist[512];
    __shared__ float wsum[512];
    __shared__ int cur[512];
    int t = threadIdx.x;
    int b = blockIdx.x;
    int bb = bbase[b], be = bbase[b + 1];
    int Ki = be - bb;
    if (t < 512) { hist[t] = 0; wsum[t] = 0.0f; }
    __syncthreads();
    for (int i = t; i < Ki; i += 1024) {
        ull p = pool[bb + i];
        unsigned hi = (unsigned)(p >> 32);
        int c9 = (hi >> 20) & 511;
        atomicAdd(&hist[c9], 1);
        atomicAdd(&wsum[c9], __uint_as_float((unsigned)p));
    }
    __syncthreads();
    int own = (t < 512) ? hist[t] : 0;
    if (t < 512) cur[t] = own;
    __syncthreads();
    for (int off = 1; off < 512; off <<= 1) {
        int v = (t >= off && t < 512) ? cur[t - off] : 0;
        __syncthreads();
        if (t < 512) cur[t] += v;
        __syncthreads();
    }
    int excl = (t < 512) ? (cur[t] - own) : 0;
    if (t < 512) cur[t] = excl;
    int c = (b << 9) + t;
    if (t < 512 && c < N) {
        rowptr[c] = bb + excl;
        dinv[c] = rsqrtf(1.0f + wsum[t]);       // deg = self(1) + sum(w)
    }
    __syncthreads();
    for (int i = t; i < Ki; i += 1024) {
        ull p = pool[bb + i];
        unsigned hi = (unsigned)(p >> 32);
        int c9 = (hi >> 20) & 511;
        unsigned r = hi & 0xFFFFFu;             // < N < 2^17
        unsigned lo = (unsigned)p;              // f32 bits of w (positive)
        unsigned w15 = (lo + 0x8000u) >> 16;    // RNE to 15-bit (8e+7m)
        int k = atomicAdd(&cur[c9], 1);
        csr[bb + k] = (w15 << 17) | r;
    }
}

// ---------- GEMM1 (split-K=4, no LDS, full-line loads): part[q][row][f] ----------
__device__ __forceinline__ void fma16(float av, const float* __restrict__ wrow,
                                      float* __restrict__ acc) {
#pragma unroll
    for (int f = 0; f < NF1; f++) acc[f] = fmaf(av, wrow[f], acc[f]);
}

__global__ __launch_bounds__(256) void gemm1_kernel(const float* __restrict__ x,
                                                    const float* __restrict__ W1,
                                                    float* __restrict__ part,
                                                    int N, int nbRow) {
    int b = blockIdx.x;
    int q = b / nbRow;                 // K-quarter 0..3
    int rb = b - q * nbRow;
    int row = rb * 256 + threadIdx.x;
    if (row >= N) return;
    const int k0 = q * (FIN / SK);     // 128 per quarter

    float acc[NF1];
#pragma unroll
    for (int f = 0; f < NF1; f++) acc[f] = 0.0f;

    const float* xr = x + (size_t)row * FIN + k0;
    const float* wp = W1 + (size_t)k0 * NF1;

#pragma unroll 2
    for (int k = 0; k < FIN / SK; k += 16) {
        const float4* xp = reinterpret_cast<const float4*>(xr + k);
        float4 a0 = xp[0];
        float4 a1 = xp[1];
        float4 a2 = xp[2];
        float4 a3 = xp[3];
        const float* wk = wp + (size_t)k * NF1;
        fma16(a0.x, wk + 0 * NF1, acc);
        fma16(a0.y, wk + 1 * NF1, acc);
        fma16(a0.z, wk + 2 * NF1, acc);
        fma16(a0.w, wk + 3 * NF1, acc);
        fma16(a1.x, wk + 4 * NF1, acc);
        fma16(a1.y, wk + 5 * NF1, acc);
        fma16(a1.z, wk + 6 * NF1, acc);
        fma16(a1.w, wk + 7 * NF1, acc);
        fma16(a2.x, wk + 8 * NF1, acc);
        fma16(a2.y, wk + 9 * NF1, acc);
        fma16(a2.z, wk + 10 * NF1, acc);
        fma16(a2.w, wk + 11 * NF1, acc);
        fma16(a3.x, wk + 12 * NF1, acc);
        fma16(a3.y, wk + 13 * NF1, acc);
        fma16(a3.z, wk + 14 * NF1, acc);
        fma16(a3.w, wk + 15 * NF1, acc);
    }

    float* pp = part + ((size_t)q * N + row) * NF1;
#pragma unroll
    for (int qq = 0; qq < 4; qq++) {
        float4 o = make_float4(acc[4 * qq], acc[4 * qq + 1], acc[4 * qq + 2], acc[4 * qq + 3]);
        *reinterpret_cast<float4*>(pp + 4 * qq) = o;
    }
}

// ---------- combine split-K partials, fold dinv, pack bf16: hs16 = bf16(dinv*(Σp)) ----------
__global__ __launch_bounds__(256) void combine_scale_kernel(const float* __restrict__ part,
                                                            const float* __restrict__ dinv,
                                                            us* __restrict__ hs16, int N) {
    int i4 = blockIdx.x * 256 + threadIdx.x;     // 4-float chunk index
    int total = N * NF1 / 4;
    if (i4 >= total) return;
    int rowIdx = i4 >> 2;                        // 4 chunks per row
    const float4* p0 = reinterpret_cast<const float4*>(part);
    const float4* p1 = reinterpret_cast<const float4*>(part + (size_t)1 * N * NF1);
    const float4* p2 = reinterpret_cast<const float4*>(part + (size_t)2 * N * NF1);
    const float4* p3 = reinterpret_cast<const float4*>(part + (size_t)3 * N * NF1);
    float4 a = p0[i4], b = p1[i4], c = p2[i4], d4 = p3[i4];
    float d = dinv[rowIdx];
    ushort4 u;
    u.x = f2bf(d * (a.x + b.x + c.x + d4.x));
    u.y = f2bf(d * (a.y + b.y + c.y + d4.y));
    u.z = f2bf(d * (a.z + b.z + c.z + d4.z));
    u.w = f2bf(d * (a.w + b.w + c.w + d4.w));
    reinterpret_cast<ushort4*>(hs16)[i4] = u;
}

// ---------- gather layer 1: x1[c] = b1 + di*( sum w_i*hs[r_i] + hs[c] ) ----------
__global__ __launch_bounds__(256) void gather1_kernel(const unsigned* __restrict__ csr,
                                                      const int* __restrict__ rowptr,
                                                      const float* __restrict__ dinv,
                                                      const us* __restrict__ hs16,
                                                      const float* __restrict__ b1,
                                                      float* __restrict__ x1, int N) {
    int t = blockIdx.x * 256 + threadIdx.x;
    int node = t >> 4, f = t & 15;
    if (node >= N) return;
    int s = rowptr[node], e = rowptr[node + 1];
    float di = dinv[node];
    float acc = bf2f(hs16[(size_t)node * NF1 + f]);   // self-loop: hs[c]
    int i = s;
    for (; i + 1 < e; i += 2) {
        unsigned e0 = csr[i], e1 = csr[i + 1];
        int r0 = e0 & 0x1FFFF; float w0 = w15f(e0);
        int r1 = e1 & 0x1FFFF; float w1 = w15f(e1);
        acc += w0 * bf2f(hs16[(size_t)r0 * NF1 + f]);
        acc += w1 * bf2f(hs16[(size_t)r1 * NF1 + f]);
    }
    if (i < e) {
        unsigned e0 = csr[i];
        int r = e0 & 0x1FFFF; float w = w15f(e0);
        acc += w * bf2f(hs16[(size_t)r * NF1 + f]);
    }
    x1[(size_t)node * NF1 + f] = b1[f] + di * acc;
}

// ---------- GEMM2: hh16 = bf16( dinv[j] * (relu(x1[j]) @ W2) ) ----------
__global__ __launch_bounds__(256) void gemm2_kernel(const float* __restrict__ x1,
                                                    const float* __restrict__ W2,
                                                    const float* __restrict__ dinv,
                                                    us* __restrict__ hh16, int N) {
    int j = blockIdx.x * 256 + threadIdx.x;
    if (j >= N) return;
    float xr[NF1];
#pragma unroll
    for (int f = 0; f < NF1; f++) xr[f] = fmaxf(x1[(size_t)j * NF1 + f], 0.0f);
    float d = dinv[j];
    float o[NF2];
#pragma unroll
    for (int c = 0; c < NF2; c++) {
        float acc = 0.0f;
#pragma unroll
        for (int f = 0; f < NF1; f++) acc += xr[f] * W2[f * NF2 + c];
        o[c] = d * acc;
    }
    // pack 10 bf16 as 5 uints (row offset j*20 B is 4B-aligned)
    unsigned* hp = reinterpret_cast<unsigned*>(const_cast<us*>(hh16) + (size_t)j * NF2);
#pragma unroll
    for (int cp = 0; cp < 5; cp++)
        hp[cp] = (unsigned)f2bf(o[2 * cp]) | ((unsigned)f2bf(o[2 * cp + 1]) << 16);
}

// ---------- gather layer 2 + fused log-softmax ----------
__global__ __launch_bounds__(256) void gather2_lsm_kernel(const unsigned* __restrict__ csr,
                                                          const int* __restrict__ rowptr,
                                                          const float* __restrict__ dinv,
                                                          const us* __restrict__ hh16,
                                                          const float* __restrict__ b2,
                                                          float* __restrict__ out, int N) {
    int t = blockIdx.x * 256 + threadIdx.x;
    int node = t >> 4, f = t & 15;
    bool act = (node < N) && (f < NF2);
    float acc = 0.0f;
    if (node < N) {
        int s = rowptr[node], e = rowptr[node + 1];
        float di = dinv[node];
        acc = act ? bf2f(hh16[(size_t)node * NF2 + f]) : 0.0f;   // self-loop
        int i = s;
        for (; i + 1 < e; i += 2) {
            unsigned e0 = csr[i], e1 = csr[i + 1];
            int r0 = e0 & 0x1FFFF; float w0 = w15f(e0);
            int r1 = e1 & 0x1FFFF; float w1 = w15f(e1);
            float h0 = (f < NF2) ? bf2f(hh16[(size_t)r0 * NF2 + f]) : 0.0f;
            float h1 = (f < NF2) ? bf2f(hh16[(size_t)r1 * NF2 + f]) : 0.0f;
            acc += w0 * h0 + w1 * h1;
        }
        if (i < e) {
            unsigned e0 = csr[i];
            int r = e0 & 0x1FFFF; float w = w15f(e0);
            float hv = (f < NF2) ? bf2f(hh16[(size_t)r * NF2 + f]) : 0.0f;
            acc += w * hv;
        }
        acc = b2[f] + di * acc;
    }
    // log-softmax across the 16-lane group (10 active lanes)
    float m = act ? acc : -INFINITY;
#pragma unroll
    for (int off = 1; off < 16; off <<= 1) m = fmaxf(m, __shfl_xor(m, off, 16));
    float p = act ? expf(acc - m) : 0.0f;
    float ssum = p;
#pragma unroll
    for (int off = 1; off < 16; off <<= 1) ssum += __shfl_xor(ssum, off, 16);
    if (act) out[(size_t)node * NF2 + f] = acc - m - logf(ssum);
}

extern "C" void kernel_launch(void* const* d_in, const int* in_sizes, int n_in,
                              void* d_out, int out_size, void* d_ws, size_t ws_size,
                              hipStream_t stream) {
    const float* x  = (const float*)d_in[0];
    const int*   ei = (const int*)d_in[1];
    const float* ew = (const float*)d_in[2];
    const float* W1 = (const float*)d_in[3];
    const float* b1 = (const float*)d_in[4];
    const float* W2 = (const float*)d_in[5];
    const float* b2 = (const float*)d_in[6];

    const int E = in_sizes[2];           // 3,200,000
    const int N = in_sizes[0] / FIN;     // 100,000
    const int* row = ei;
    const int* col = ei + E;

    const int NB   = (N + 511) >> 9;     // coarse buckets (196)
    const int NBLK = (E + EPB - 1) / EPB;

    float* out    = (float*)d_out;
    float* logits = out;                        // [N,10]
    float* x1     = out + (size_t)N * NF2;      // [N,16]

    char* ws = (char*)d_ws;
    size_t off = 0;
    auto alloc = [&](size_t bytes) { void* p = ws + off; off += (bytes + 255) / 256 * 256; return p; };
    ull*      pool    = (ull*)     alloc((size_t)E * 8);
    unsigned* csr     = (unsigned*)alloc((size_t)E * 4);          // compressed entries
    float*    part    = (float*)   alloc((size_t)SK * N * NF1 * 4);
    us*       hs16    = (us*)      alloc((size_t)N * NF1 * 2);    // bf16 dinv*(x@W1)
    us*       hh16    = (us*)      alloc((size_t)N * NF2 * 2 + 64);
    float*    dinv    = (float*)   alloc((size_t)N * 4);
    int*      rowptr  = (int*)     alloc((size_t)(N + 1) * 4);
    int*      blkhist = (int*)     alloc((size_t)NB * NBLK * 4);
    int*      btot    = (int*)     alloc((size_t)NB * 4);
    int*      bbase   = (int*)     alloc((size_t)(NB + 1) * 4);
    (void)ws_size; (void)n_in; (void)out_size;

    dim3 blk(256);
    int gN    = (N + 255) / 256;
    int g16   = (N + 15) / 16;
    int nbRow = (N + 255) / 256;         // gemm1 row-blocks per K-quarter

    // build compressed CSR (no global atomics)
    coarse_count_kernel<<<NBLK, blk, 0, stream>>>(col, blkhist, E, NB, NBLK);
    bucket_scan_kernel<<<NB, dim3(512), 0, stream>>>(blkhist, btot, NBLK);
    base_scan_kernel<<<1, blk, 0, stream>>>(btot, bbase, rowptr, NB, E, N);
    coarse_scatter_kernel<<<NBLK, blk, 0, stream>>>(row, col, ew, blkhist, bbase, pool, E, NB, NBLK);
    fine_sort_kernel<<<NB, dim3(1024), 0, stream>>>(pool, bbase, csr, rowptr, dinv, N);

    // layer 1
    gemm1_kernel<<<SK * nbRow, blk, 0, stream>>>(x, W1, part, N, nbRow);
    combine_scale_kernel<<<(N * NF1 / 4 + 255) / 256, blk, 0, stream>>>(part, dinv, hs16, N);
    gather1_kernel<<<g16, blk, 0, stream>>>(csr, rowptr, dinv, hs16, b1, x1, N);

    // layer 2
    gemm2_kernel<<<gN, blk, 0, stream>>>(x1, W2, dinv, hh16, N);
    gather2_lsm_kernel<<<g16, blk, 0, stream>>>(csr, rowptr, dinv, hh16, b2, logits, N);
}

// Round 18
// 231.431 us; speedup vs baseline: 1.3488x; 1.1592x over previous
//
#include <hip/hip_runtime.h>
#include <hip/hip_bf16.h>

// GCN 2-layer forward on MI355X — round 18 = round-17 (best, 268us) + ONE
// change: gather loops unrolled x4. The gathers are latency-chain-bound
// (csr load -> dependent ~200cy L2 gather, only 2 in flight); issuing 4
// independent csr entries then 4 gathers doubles memory-level parallelism.
// Inputs: x[N,512] f32, edge_index[2,E] int32, edge_weight[E] f32,
//         W1[512,16], b1[16], W2[16,10], b2[10]
// Outputs (concat): log_softmax(logits)[N,10], x1[N,16]

#define NF1 16   // hidden
#define NF2 10   // classes
#define FIN 512
#define EPB 8192 // edges per coarse block (256 thr * 32)
#define SK  4    // gemm1 split-K factor

typedef unsigned long long ull;
typedef unsigned short us;

// bf16 pack/unpack (round-to-nearest-even; data has no NaN)
__device__ __forceinline__ us f2bf(float f) {
    union { float f; unsigned u; } v; v.f = f;
    unsigned r = v.u + 0x7FFFu + ((v.u >> 16) & 1u);
    return (us)(r >> 16);
}
__device__ __forceinline__ float bf2f(us h) {
    union { unsigned u; float f; } v; v.u = ((unsigned)h) << 16;
    return v.f;
}
// 15-bit positive-float weight decode: bits[30:16] stored, sign=0
__device__ __forceinline__ float w15f(unsigned e) {
    union { unsigned u; float f; } v; v.u = (e >> 17) << 16;
    return v.f;
}

// ---------- A: coarse count (col>>9) into per-block histograms ----------
__global__ __launch_bounds__(256) void coarse_count_kernel(const int* __restrict__ col,
                                                           int* __restrict__ blkhist,
                                                           int E, int NB, int NBLK) {
    __shared__ int lh[256];
    int t = threadIdx.x;
    lh[t] = 0;
    __syncthreads();
    int base = blockIdx.x * EPB;
    int cnt = min(EPB, E - base);
    for (int i = t; i < cnt; i += 256)
        atomicAdd(&lh[col[base + i] >> 9], 1);
    __syncthreads();
    if (t < NB) blkhist[t * NBLK + blockIdx.x] = lh[t];
}

// ---------- B1: per-bucket exclusive scan over blocks (parallel) ----------
__global__ __launch_bounds__(512) void bucket_scan_kernel(int* __restrict__ blkhist,
                                                          int* __restrict__ btot,
                                                          int NBLK) {
    __shared__ int s[512];
    int t = threadIdx.x;
    int* p = blkhist + (size_t)blockIdx.x * NBLK;
    int carry = 0;
    for (int base = 0; base < NBLK; base += 512) {
        int idx = base + t;
        int v = (idx < NBLK) ? p[idx] : 0;
        s[t] = v;
        __syncthreads();
        for (int off = 1; off < 512; off <<= 1) {
            int u = (t >= off) ? s[t - off] : 0;
            __syncthreads();
            s[t] += u;
            __syncthreads();
        }
        if (idx < NBLK) p[idx] = s[t] - v + carry;
        carry += s[511];
        __syncthreads();
    }
    if (t == 0) btot[blockIdx.x] = carry;
}

// ---------- B2: scan bucket totals -> bbase ----------
__global__ __launch_bounds__(256) void base_scan_kernel(const int* __restrict__ btot,
                                                        int* __restrict__ bbase,
                                                        int* __restrict__ rowptr,
                                                        int NB, int E, int N) {
    __shared__ int s[256];
    int t = threadIdx.x;
    int v = (t < NB) ? btot[t] : 0;
    s[t] = v;
    __syncthreads();
    for (int off = 1; off < 256; off <<= 1) {
        int u = (t >= off) ? s[t - off] : 0;
        __syncthreads();
        s[t] += u;
        __syncthreads();
    }
    if (t < NB) bbase[t] = s[t] - v;
    if (t == 0) { bbase[NB] = E; rowptr[N] = E; }
}

// ---------- C: coarse scatter into bucket-ordered pool ----------
// pool entry: hi32 = (c9<<20)|row, lo32 = weight bits (f32)
__global__ __launch_bounds__(256) void coarse_scatter_kernel(const int* __restrict__ row,
                                                             const int* __restrict__ col,
                                                             const float* __restrict__ ew,
                                                             const int* __restrict__ blkhist,
                                                             const int* __restrict__ bbase,
                                                             ull* __restrict__ pool,
                                                             int E, int NB, int NBLK) {
    __shared__ int cur[256];
    int t = threadIdx.x;
    if (t < NB) cur[t] = blkhist[t * NBLK + blockIdx.x] + bbase[t];
    __syncthreads();
    int base = blockIdx.x * EPB;
    int cnt = min(EPB, E - base);
    for (int i = t; i < cnt; i += 256) {
        int e = base + i;
        int c = col[e], r = row[e];
        float w = ew[e];
        int b = c >> 9, c9 = c & 511;
        int pos = atomicAdd(&cur[b], 1);
        pool[pos] = ((ull)((((unsigned)c9) << 20) | (unsigned)r) << 32) | (ull)__float_as_uint(w);
    }
}

// ---------- D: fine sort within bucket -> compressed CSR, rowptr, dinv ----------
__global__ __launch_bounds__(1024) void fine_sort_kernel(const ull* __restrict__ pool,
                                                         const int* __restrict__ bbase,
                                                         unsigned* __restrict__ csr,
                                                         int* __restrict__ rowptr,
                                                         float* __restrict__ dinv, int N) {
    __shared__ int hist[512];
    __shared__ float wsum[512];
    __shared__ int cur[512];
    int t = threadIdx.x;
    int b = blockIdx.x;
    int bb = bbase[b], be = bbase[b + 1];
    int Ki = be - bb;
    if (t < 512) { hist[t] = 0; wsum[t] = 0.0f; }
    __syncthreads();
    for (int i = t; i < Ki; i += 1024) {
        ull p = pool[bb + i];
        unsigned hi = (unsigned)(p >> 32);
        int c9 = (hi >> 20) & 511;
        atomicAdd(&hist[c9], 1);
        atomicAdd(&wsum[c9], __uint_as_float((unsigned)p));
    }
    __syncthreads();
    int own = (t < 512) ? hist[t] : 0;
    if (t < 512) cur[t] = own;
    __syncthreads();
    for (int off = 1; off < 512; off <<= 1) {
        int v = (t >= off && t < 512) ? cur[t - off] : 0;
        __syncthreads();
        if (t < 512) cur[t] += v;
        __syncthreads();
    }
    int excl = (t < 512) ? (cur[t] - own) : 0;
    if (t < 512) cur[t] = excl;
    int c = (b << 9) + t;
    if (t < 512 && c < N) {
        rowptr[c] = bb + excl;
        dinv[c] = rsqrtf(1.0f + wsum[t]);       // deg = self(1) + sum(w)
    }
    __syncthreads();
    for (int i = t; i < Ki; i += 1024) {
        ull p = pool[bb + i];
        unsigned hi = (unsigned)(p >> 32);
        int c9 = (hi >> 20) & 511;
        unsigned r = hi & 0xFFFFFu;             // < N < 2^17
        unsigned lo = (unsigned)p;              // f32 bits of w (positive)
        unsigned w15 = (lo + 0x8000u) >> 16;    // RNE to 15-bit (8e+7m)
        int k = atomicAdd(&cur[c9], 1);
        csr[bb + k] = (w15 << 17) | r;
    }
}

// ---------- GEMM1 (split-K=4, no LDS, full-line loads): part[q][row][f] ----------
__device__ __forceinline__ void fma16(float av, const float* __restrict__ wrow,
                                      float* __restrict__ acc) {
#pragma unroll
    for (int f = 0; f < NF1; f++) acc[f] = fmaf(av, wrow[f], acc[f]);
}

__global__ __launch_bounds__(256) void gemm1_kernel(const float* __restrict__ x,
                                                    const float* __restrict__ W1,
                                                    float* __restrict__ part,
                                                    int N, int nbRow) {
    int b = blockIdx.x;
    int q = b / nbRow;                 // K-quarter 0..3
    int rb = b - q * nbRow;
    int row = rb * 256 + threadIdx.x;
    if (row >= N) return;
    const int k0 = q * (FIN / SK);     // 128 per quarter

    float acc[NF1];
#pragma unroll
    for (int f = 0; f < NF1; f++) acc[f] = 0.0f;

    const float* xr = x + (size_t)row * FIN + k0;
    const float* wp = W1 + (size_t)k0 * NF1;

#pragma unroll 2
    for (int k = 0; k < FIN / SK; k += 16) {
        const float4* xp = reinterpret_cast<const float4*>(xr + k);
        float4 a0 = xp[0];
        float4 a1 = xp[1];
        float4 a2 = xp[2];
        float4 a3 = xp[3];
        const float* wk = wp + (size_t)k * NF1;
        fma16(a0.x, wk + 0 * NF1, acc);
        fma16(a0.y, wk + 1 * NF1, acc);
        fma16(a0.z, wk + 2 * NF1, acc);
        fma16(a0.w, wk + 3 * NF1, acc);
        fma16(a1.x, wk + 4 * NF1, acc);
        fma16(a1.y, wk + 5 * NF1, acc);
        fma16(a1.z, wk + 6 * NF1, acc);
        fma16(a1.w, wk + 7 * NF1, acc);
        fma16(a2.x, wk + 8 * NF1, acc);
        fma16(a2.y, wk + 9 * NF1, acc);
        fma16(a2.z, wk + 10 * NF1, acc);
        fma16(a2.w, wk + 11 * NF1, acc);
        fma16(a3.x, wk + 12 * NF1, acc);
        fma16(a3.y, wk + 13 * NF1, acc);
        fma16(a3.z, wk + 14 * NF1, acc);
        fma16(a3.w, wk + 15 * NF1, acc);
    }

    float* pp = part + ((size_t)q * N + row) * NF1;
#pragma unroll
    for (int qq = 0; qq < 4; qq++) {
        float4 o = make_float4(acc[4 * qq], acc[4 * qq + 1], acc[4 * qq + 2], acc[4 * qq + 3]);
        *reinterpret_cast<float4*>(pp + 4 * qq) = o;
    }
}

// ---------- combine split-K partials, fold dinv, pack bf16: hs16 = bf16(dinv*(Σp)) ----------
__global__ __launch_bounds__(256) void combine_scale_kernel(const float* __restrict__ part,
                                                            const float* __restrict__ dinv,
                                                            us* __restrict__ hs16, int N) {
    int i4 = blockIdx.x * 256 + threadIdx.x;     // 4-float chunk index
    int total = N * NF1 / 4;
    if (i4 >= total) return;
    int rowIdx = i4 >> 2;                        // 4 chunks per row
    const float4* p0 = reinterpret_cast<const float4*>(part);
    const float4* p1 = reinterpret_cast<const float4*>(part + (size_t)1 * N * NF1);
    const float4* p2 = reinterpret_cast<const float4*>(part + (size_t)2 * N * NF1);
    const float4* p3 = reinterpret_cast<const float4*>(part + (size_t)3 * N * NF1);
    float4 a = p0[i4], b = p1[i4], c = p2[i4], d4 = p3[i4];
    float d = dinv[rowIdx];
    ushort4 u;
    u.x = f2bf(d * (a.x + b.x + c.x + d4.x));
    u.y = f2bf(d * (a.y + b.y + c.y + d4.y));
    u.z = f2bf(d * (a.z + b.z + c.z + d4.z));
    u.w = f2bf(d * (a.w + b.w + c.w + d4.w));
    reinterpret_cast<ushort4*>(hs16)[i4] = u;
}

// ---------- gather layer 1 (x4 unroll): x1[c] = b1 + di*( sum w_i*hs[r_i] + hs[c] ) ----------
__global__ __launch_bounds__(256) void gather1_kernel(const unsigned* __restrict__ csr,
                                                      const int* __restrict__ rowptr,
                                                      const float* __restrict__ dinv,
                                                      const us* __restrict__ hs16,
                                                      const float* __restrict__ b1,
                                                      float* __restrict__ x1, int N) {
    int t = blockIdx.x * 256 + threadIdx.x;
    int node = t >> 4, f = t & 15;
    if (node >= N) return;
    int s = rowptr[node], e = rowptr[node + 1];
    float di = dinv[node];
    float acc = bf2f(hs16[(size_t)node * NF1 + f]);   // self-loop: hs[c]
    int i = s;
    for (; i + 3 < e; i += 4) {
        unsigned e0 = csr[i], e1 = csr[i + 1], e2 = csr[i + 2], e3 = csr[i + 3];
        float h0 = bf2f(hs16[(size_t)(e0 & 0x1FFFF) * NF1 + f]);
        float h1 = bf2f(hs16[(size_t)(e1 & 0x1FFFF) * NF1 + f]);
        float h2 = bf2f(hs16[(size_t)(e2 & 0x1FFFF) * NF1 + f]);
        float h3 = bf2f(hs16[(size_t)(e3 & 0x1FFFF) * NF1 + f]);
        acc += w15f(e0) * h0;
        acc += w15f(e1) * h1;
        acc += w15f(e2) * h2;
        acc += w15f(e3) * h3;
    }
    for (; i < e; i++) {
        unsigned e0 = csr[i];
        acc += w15f(e0) * bf2f(hs16[(size_t)(e0 & 0x1FFFF) * NF1 + f]);
    }
    x1[(size_t)node * NF1 + f] = b1[f] + di * acc;
}

// ---------- GEMM2: hh16 = bf16( dinv[j] * (relu(x1[j]) @ W2) ) ----------
__global__ __launch_bounds__(256) void gemm2_kernel(const float* __restrict__ x1,
                                                    const float* __restrict__ W2,
                                                    const float* __restrict__ dinv,
                                                    us* __restrict__ hh16, int N) {
    int j = blockIdx.x * 256 + threadIdx.x;
    if (j >= N) return;
    float xr[NF1];
#pragma unroll
    for (int f = 0; f < NF1; f++) xr[f] = fmaxf(x1[(size_t)j * NF1 + f], 0.0f);
    float d = dinv[j];
    float o[NF2];
#pragma unroll
    for (int c = 0; c < NF2; c++) {
        float acc = 0.0f;
#pragma unroll
        for (int f = 0; f < NF1; f++) acc += xr[f] * W2[f * NF2 + c];
        o[c] = d * acc;
    }
    // pack 10 bf16 as 5 uints (row offset j*20 B is 4B-aligned)
    unsigned* hp = reinterpret_cast<unsigned*>(const_cast<us*>(hh16) + (size_t)j * NF2);
#pragma unroll
    for (int cp = 0; cp < 5; cp++)
        hp[cp] = (unsigned)f2bf(o[2 * cp]) | ((unsigned)f2bf(o[2 * cp + 1]) << 16);
}

// ---------- gather layer 2 (x4 unroll) + fused log-softmax ----------
__global__ __launch_bounds__(256) void gather2_lsm_kernel(const unsigned* __restrict__ csr,
                                                          const int* __restrict__ rowptr,
                                                          const float* __restrict__ dinv,
                                                          const us* __restrict__ hh16,
                                                          const float* __restrict__ b2,
                                                          float* __restrict__ out, int N) {
    int t = blockIdx.x * 256 + threadIdx.x;
    int node = t >> 4, f = t & 15;
    bool act = (node < N) && (f < NF2);
    float acc = 0.0f;
    if (node < N) {
        int s = rowptr[node], e = rowptr[node + 1];
        float di = dinv[node];
        acc = act ? bf2f(hh16[(size_t)node * NF2 + f]) : 0.0f;   // self-loop
        int i = s;
        if (f < NF2) {
            for (; i + 3 < e; i += 4) {
                unsigned e0 = csr[i], e1 = csr[i + 1], e2 = csr[i + 2], e3 = csr[i + 3];
                float h0 = bf2f(hh16[(size_t)(e0 & 0x1FFFF) * NF2 + f]);
                float h1 = bf2f(hh16[(size_t)(e1 & 0x1FFFF) * NF2 + f]);
                float h2 = bf2f(hh16[(size_t)(e2 & 0x1FFFF) * NF2 + f]);
                float h3 = bf2f(hh16[(size_t)(e3 & 0x1FFFF) * NF2 + f]);
                acc += w15f(e0) * h0;
                acc += w15f(e1) * h1;
                acc += w15f(e2) * h2;
                acc += w15f(e3) * h3;
            }
            for (; i < e; i++) {
                unsigned e0 = csr[i];
                acc += w15f(e0) * bf2f(hh16[(size_t)(e0 & 0x1FFFF) * NF2 + f]);
            }
        }
        acc = b2[f] + di * acc;  // garbage in lanes f>=10, masked below
    }
    // log-softmax across the 16-lane group (10 active lanes)
    float m = act ? acc : -INFINITY;
#pragma unroll
    for (int off = 1; off < 16; off <<= 1) m = fmaxf(m, __shfl_xor(m, off, 16));
    float p = act ? expf(acc - m) : 0.0f;
    float ssum = p;
#pragma unroll
    for (int off = 1; off < 16; off <<= 1) ssum += __shfl_xor(ssum, off, 16);
    if (act) out[(size_t)node * NF2 + f] = acc - m - logf(ssum);
}

extern "C" void kernel_launch(void* const* d_in, const int* in_sizes, int n_in,
                              void* d_out, int out_size, void* d_ws, size_t ws_size,
                              hipStream_t stream) {
    const float* x  = (const float*)d_in[0];
    const int*   ei = (const int*)d_in[1];
    const float* ew = (const float*)d_in[2];
    const float* W1 = (const float*)d_in[3];
    const float* b1 = (const float*)d_in[4];
    const float* W2 = (const float*)d_in[5];
    const float* b2 = (const float*)d_in[6];

    const int E = in_sizes[2];           // 3,200,000
    const int N = in_sizes[0] / FIN;     // 100,000
    const int* row = ei;
    const int* col = ei + E;

    const int NB   = (N + 511) >> 9;     // coarse buckets (196)
    const int NBLK = (E + EPB - 1) / EPB;

    float* out    = (float*)d_out;
    float* logits = out;                        // [N,10]
    float* x1     = out + (size_t)N * NF2;      // [N,16]

    char* ws = (char*)d_ws;
    size_t off = 0;
    auto alloc = [&](size_t bytes) { void* p = ws + off; off += (bytes + 255) / 256 * 256; return p; };
    ull*      pool    = (ull*)     alloc((size_t)E * 8);
    unsigned* csr     = (unsigned*)alloc((size_t)E * 4);          // compressed entries
    float*    part    = (float*)   alloc((size_t)SK * N * NF1 * 4);
    us*       hs16    = (us*)      alloc((size_t)N * NF1 * 2);    // bf16 dinv*(x@W1)
    us*       hh16    = (us*)      alloc((size_t)N * NF2 * 2 + 64);
    float*    dinv    = (float*)   alloc((size_t)N * 4);
    int*      rowptr  = (int*)     alloc((size_t)(N + 1) * 4);
    int*      blkhist = (int*)     alloc((size_t)NB * NBLK * 4);
    int*      btot    = (int*)     alloc((size_t)NB * 4);
    int*      bbase   = (int*)     alloc((size_t)(NB + 1) * 4);
    (void)ws_size; (void)n_in; (void)out_size;

    dim3 blk(256);
    int gN    = (N + 255) / 256;
    int g16   = (N + 15) / 16;
    int nbRow = (N + 255) / 256;         // gemm1 row-blocks per K-quarter

    // build compressed CSR (no global atomics)
    coarse_count_kernel<<<NBLK, blk, 0, stream>>>(col, blkhist, E, NB, NBLK);
    bucket_scan_kernel<<<NB, dim3(512), 0, stream>>>(blkhist, btot, NBLK);
    base_scan_kernel<<<1, blk, 0, stream>>>(btot, bbase, rowptr, NB, E, N);
    coarse_scatter_kernel<<<NBLK, blk, 0, stream>>>(row, col, ew, blkhist, bbase, pool, E, NB, NBLK);
    fine_sort_kernel<<<NB, dim3(1024), 0, stream>>>(pool, bbase, csr, rowptr, dinv, N);

    // layer 1
    gemm1_kernel<<<SK * nbRow, blk, 0, stream>>>(x, W1, part, N, nbRow);
    combine_scale_kernel<<<(N * NF1 / 4 + 255) / 256, blk, 0, stream>>>(part, dinv, hs16, N);
    gather1_kernel<<<g16, blk, 0, stream>>>(csr, rowptr, dinv, hs16, b1, x1, N);

    // layer 2
    gemm2_kernel<<<gN, blk, 0, stream>>>(x1, W2, dinv, hh16, N);
    gather2_lsm_kernel<<<g16, blk, 0, stream>>>(csr, rowptr, dinv, hh16, b2, logits, N);
}

// Round 19
// 228.269 us; speedup vs baseline: 1.3675x; 1.0139x over previous
//
#include <hip/hip_runtime.h>
#include <hip/hip_bf16.h>

// GCN 2-layer forward on MI355X — round 19 = round-18 (best, 231us) with the
// proven MLP-unroll lever pushed further: gathers x4 -> x8, and fine_sort's
// two pool passes batched x4 (4 independent loads issued before the LDS-atomic
// chains). Pure ILP restructuring; no layout/precision/grid changes.
// Inputs: x[N,512] f32, edge_index[2,E] int32, edge_weight[E] f32,
//         W1[512,16], b1[16], W2[16,10], b2[10]
// Outputs (concat): log_softmax(logits)[N,10], x1[N,16]

#define NF1 16   // hidden
#define NF2 10   // classes
#define FIN 512
#define EPB 8192 // edges per coarse block (256 thr * 32)
#define SK  4    // gemm1 split-K factor

typedef unsigned long long ull;
typedef unsigned short us;

// bf16 pack/unpack (round-to-nearest-even; data has no NaN)
__device__ __forceinline__ us f2bf(float f) {
    union { float f; unsigned u; } v; v.f = f;
    unsigned r = v.u + 0x7FFFu + ((v.u >> 16) & 1u);
    return (us)(r >> 16);
}
__device__ __forceinline__ float bf2f(us h) {
    union { unsigned u; float f; } v; v.u = ((unsigned)h) << 16;
    return v.f;
}
// 15-bit positive-float weight decode: bits[30:16] stored, sign=0
__device__ __forceinline__ float w15f(unsigned e) {
    union { unsigned u; float f; } v; v.u = (e >> 17) << 16;
    return v.f;
}

// ---------- A: coarse count (col>>9) into per-block histograms ----------
__global__ __launch_bounds__(256) void coarse_count_kernel(const int* __restrict__ col,
                                                           int* __restrict__ blkhist,
                                                           int E, int NB, int NBLK) {
    __shared__ int lh[256];
    int t = threadIdx.x;
    lh[t] = 0;
    __syncthreads();
    int base = blockIdx.x * EPB;
    int cnt = min(EPB, E - base);
    for (int i = t; i < cnt; i += 256)
        atomicAdd(&lh[col[base + i] >> 9], 1);
    __syncthreads();
    if (t < NB) blkhist[t * NBLK + blockIdx.x] = lh[t];
}

// ---------- B1: per-bucket exclusive scan over blocks (parallel) ----------
__global__ __launch_bounds__(512) void bucket_scan_kernel(int* __restrict__ blkhist,
                                                          int* __restrict__ btot,
                                                          int NBLK) {
    __shared__ int s[512];
    int t = threadIdx.x;
    int* p = blkhist + (size_t)blockIdx.x * NBLK;
    int carry = 0;
    for (int base = 0; base < NBLK; base += 512) {
        int idx = base + t;
        int v = (idx < NBLK) ? p[idx] : 0;
        s[t] = v;
        __syncthreads();
        for (int off = 1; off < 512; off <<= 1) {
            int u = (t >= off) ? s[t - off] : 0;
            __syncthreads();
            s[t] += u;
            __syncthreads();
        }
        if (idx < NBLK) p[idx] = s[t] - v + carry;
        carry += s[511];
        __syncthreads();
    }
    if (t == 0) btot[blockIdx.x] = carry;
}

// ---------- B2: scan bucket totals -> bbase ----------
__global__ __launch_bounds__(256) void base_scan_kernel(const int* __restrict__ btot,
                                                        int* __restrict__ bbase,
                                                        int* __restrict__ rowptr,
                                                        int NB, int E, int N) {
    __shared__ int s[256];
    int t = threadIdx.x;
    int v = (t < NB) ? btot[t] : 0;
    s[t] = v;
    __syncthreads();
    for (int off = 1; off < 256; off <<= 1) {
        int u = (t >= off) ? s[t - off] : 0;
        __syncthreads();
        s[t] += u;
        __syncthreads();
    }
    if (t < NB) bbase[t] = s[t] - v;
    if (t == 0) { bbase[NB] = E; rowptr[N] = E; }
}

// ---------- C: coarse scatter into bucket-ordered pool ----------
// pool entry: hi32 = (c9<<20)|row, lo32 = weight bits (f32)
__global__ __launch_bounds__(256) void coarse_scatter_kernel(const int* __restrict__ row,
                                                             const int* __restrict__ col,
                                                             const float* __restrict__ ew,
                                                             const int* __restrict__ blkhist,
                                                             const int* __restrict__ bbase,
                                                             ull* __restrict__ pool,
                                                             int E, int NB, int NBLK) {
    __shared__ int cur[256];
    int t = threadIdx.x;
    if (t < NB) cur[t] = blkhist[t * NBLK + blockIdx.x] + bbase[t];
    __syncthreads();
    int base = blockIdx.x * EPB;
    int cnt = min(EPB, E - base);
    for (int i = t; i < cnt; i += 256) {
        int e = base + i;
        int c = col[e], r = row[e];
        float w = ew[e];
        int b = c >> 9, c9 = c & 511;
        int pos = atomicAdd(&cur[b], 1);
        pool[pos] = ((ull)((((unsigned)c9) << 20) | (unsigned)r) << 32) | (ull)__float_as_uint(w);
    }
}

// ---------- D: fine sort within bucket -> compressed CSR, rowptr, dinv ----------
__global__ __launch_bounds__(1024) void fine_sort_kernel(const ull* __restrict__ pool,
                                                         const int* __restrict__ bbase,
                                                         unsigned* __restrict__ csr,
                                                         int* __restrict__ rowptr,
                                                         float* __restrict__ dinv, int N) {
    __shared__ int hist[512];
    __shared__ float wsum[512];
    __shared__ int cur[512];
    int t = threadIdx.x;
    int b = blockIdx.x;
    int bb = bbase[b], be = bbase[b + 1];
    int Ki = be - bb;
    if (t < 512) { hist[t] = 0; wsum[t] = 0.0f; }
    __syncthreads();
    // pass 1: hist + wsum, x4-batched loads
    int i = t;
    for (; i + 3 * 1024 < Ki; i += 4 * 1024) {
        ull p0 = pool[bb + i];
        ull p1 = pool[bb + i + 1024];
        ull p2 = pool[bb + i + 2048];
        ull p3 = pool[bb + i + 3072];
        unsigned h0 = (unsigned)(p0 >> 32), h1 = (unsigned)(p1 >> 32);
        unsigned h2 = (unsigned)(p2 >> 32), h3 = (unsigned)(p3 >> 32);
        atomicAdd(&hist[(h0 >> 20) & 511], 1);
        atomicAdd(&wsum[(h0 >> 20) & 511], __uint_as_float((unsigned)p0));
        atomicAdd(&hist[(h1 >> 20) & 511], 1);
        atomicAdd(&wsum[(h1 >> 20) & 511], __uint_as_float((unsigned)p1));
        atomicAdd(&hist[(h2 >> 20) & 511], 1);
        atomicAdd(&wsum[(h2 >> 20) & 511], __uint_as_float((unsigned)p2));
        atomicAdd(&hist[(h3 >> 20) & 511], 1);
        atomicAdd(&wsum[(h3 >> 20) & 511], __uint_as_float((unsigned)p3));
    }
    for (; i < Ki; i += 1024) {
        ull p = pool[bb + i];
        unsigned hi = (unsigned)(p >> 32);
        int c9 = (hi >> 20) & 511;
        atomicAdd(&hist[c9], 1);
        atomicAdd(&wsum[c9], __uint_as_float((unsigned)p));
    }
    __syncthreads();
    int own = (t < 512) ? hist[t] : 0;
    if (t < 512) cur[t] = own;
    __syncthreads();
    for (int off = 1; off < 512; off <<= 1) {
        int v = (t >= off && t < 512) ? cur[t - off] : 0;
        __syncthreads();
        if (t < 512) cur[t] += v;
        __syncthreads();
    }
    int excl = (t < 512) ? (cur[t] - own) : 0;
    if (t < 512) cur[t] = excl;
    int c = (b << 9) + t;
    if (t < 512 && c < N) {
        rowptr[c] = bb + excl;
        dinv[c] = rsqrtf(1.0f + wsum[t]);       // deg = self(1) + sum(w)
    }
    __syncthreads();
    // pass 2: place, x4-batched loads
    i = t;
    for (; i + 3 * 1024 < Ki; i += 4 * 1024) {
        ull p0 = pool[bb + i];
        ull p1 = pool[bb + i + 1024];
        ull p2 = pool[bb + i + 2048];
        ull p3 = pool[bb + i + 3072];
#pragma unroll
        for (int j = 0; j < 4; j++) {
            ull p = (j == 0) ? p0 : (j == 1) ? p1 : (j == 2) ? p2 : p3;
            unsigned hi = (unsigned)(p >> 32);
            int c9 = (hi >> 20) & 511;
            unsigned r = hi & 0xFFFFFu;
            unsigned lo = (unsigned)p;
            unsigned w15 = (lo + 0x8000u) >> 16;
            int k = atomicAdd(&cur[c9], 1);
            csr[bb + k] = (w15 << 17) | r;
        }
    }
    for (; i < Ki; i += 1024) {
        ull p = pool[bb + i];
        unsigned hi = (unsigned)(p >> 32);
        int c9 = (hi >> 20) & 511;
        unsigned r = hi & 0xFFFFFu;
        unsigned lo = (unsigned)p;
        unsigned w15 = (lo + 0x8000u) >> 16;
        int k = atomicAdd(&cur[c9], 1);
        csr[bb + k] = (w15 << 17) | r;
    }
}

// ---------- GEMM1 (split-K=4, no LDS, full-line loads): part[q][row][f] ----------
__device__ __forceinline__ void fma16(float av, const float* __restrict__ wrow,
                                      float* __restrict__ acc) {
#pragma unroll
    for (int f = 0; f < NF1; f++) acc[f] = fmaf(av, wrow[f], acc[f]);
}

__global__ __launch_bounds__(256) void gemm1_kernel(const float* __restrict__ x,
                                                    const float* __restrict__ W1,
                                                    float* __restrict__ part,
                                                    int N, int nbRow) {
    int b = blockIdx.x;
    int q = b / nbRow;                 // K-quarter 0..3
    int rb = b - q * nbRow;
    int row = rb * 256 + threadIdx.x;
    if (row >= N) return;
    const int k0 = q * (FIN / SK);     // 128 per quarter

    float acc[NF1];
#pragma unroll
    for (int f = 0; f < NF1; f++) acc[f] = 0.0f;

    const float* xr = x + (size_t)row * FIN + k0;
    const float* wp = W1 + (size_t)k0 * NF1;

#pragma unroll 2
    for (int k = 0; k < FIN / SK; k += 16) {
        const float4* xp = reinterpret_cast<const float4*>(xr + k);
        float4 a0 = xp[0];
        float4 a1 = xp[1];
        float4 a2 = xp[2];
        float4 a3 = xp[3];
        const float* wk = wp + (size_t)k * NF1;
        fma16(a0.x, wk + 0 * NF1, acc);
        fma16(a0.y, wk + 1 * NF1, acc);
        fma16(a0.z, wk + 2 * NF1, acc);
        fma16(a0.w, wk + 3 * NF1, acc);
        fma16(a1.x, wk + 4 * NF1, acc);
        fma16(a1.y, wk + 5 * NF1, acc);
        fma16(a1.z, wk + 6 * NF1, acc);
        fma16(a1.w, wk + 7 * NF1, acc);
        fma16(a2.x, wk + 8 * NF1, acc);
        fma16(a2.y, wk + 9 * NF1, acc);
        fma16(a2.z, wk + 10 * NF1, acc);
        fma16(a2.w, wk + 11 * NF1, acc);
        fma16(a3.x, wk + 12 * NF1, acc);
        fma16(a3.y, wk + 13 * NF1, acc);
        fma16(a3.z, wk + 14 * NF1, acc);
        fma16(a3.w, wk + 15 * NF1, acc);
    }

    float* pp = part + ((size_t)q * N + row) * NF1;
#pragma unroll
    for (int qq = 0; qq < 4; qq++) {
        float4 o = make_float4(acc[4 * qq], acc[4 * qq + 1], acc[4 * qq + 2], acc[4 * qq + 3]);
        *reinterpret_cast<float4*>(pp + 4 * qq) = o;
    }
}

// ---------- combine split-K partials, fold dinv, pack bf16: hs16 = bf16(dinv*(Σp)) ----------
__global__ __launch_bounds__(256) void combine_scale_kernel(const float* __restrict__ part,
                                                            const float* __restrict__ dinv,
                                                            us* __restrict__ hs16, int N) {
    int i4 = blockIdx.x * 256 + threadIdx.x;     // 4-float chunk index
    int total = N * NF1 / 4;
    if (i4 >= total) return;
    int rowIdx = i4 >> 2;                        // 4 chunks per row
    const float4* p0 = reinterpret_cast<const float4*>(part);
    const float4* p1 = reinterpret_cast<const float4*>(part + (size_t)1 * N * NF1);
    const float4* p2 = reinterpret_cast<const float4*>(part + (size_t)2 * N * NF1);
    const float4* p3 = reinterpret_cast<const float4*>(part + (size_t)3 * N * NF1);
    float4 a = p0[i4], b = p1[i4], c = p2[i4], d4 = p3[i4];
    float d = dinv[rowIdx];
    ushort4 u;
    u.x = f2bf(d * (a.x + b.x + c.x + d4.x));
    u.y = f2bf(d * (a.y + b.y + c.y + d4.y));
    u.z = f2bf(d * (a.z + b.z + c.z + d4.z));
    u.w = f2bf(d * (a.w + b.w + c.w + d4.w));
    reinterpret_cast<ushort4*>(hs16)[i4] = u;
}

// ---------- gather layer 1 (x8 unroll): x1[c] = b1 + di*( sum w_i*hs[r_i] + hs[c] ) ----------
__global__ __launch_bounds__(256) void gather1_kernel(const unsigned* __restrict__ csr,
                                                      const int* __restrict__ rowptr,
                                                      const float* __restrict__ dinv,
                                                      const us* __restrict__ hs16,
                                                      const float* __restrict__ b1,
                                                      float* __restrict__ x1, int N) {
    int t = blockIdx.x * 256 + threadIdx.x;
    int node = t >> 4, f = t & 15;
    if (node >= N) return;
    int s = rowptr[node], e = rowptr[node + 1];
    float di = dinv[node];
    float acc = bf2f(hs16[(size_t)node * NF1 + f]);   // self-loop: hs[c]
    int i = s;
    for (; i + 7 < e; i += 8) {
        unsigned e0 = csr[i],     e1 = csr[i + 1], e2 = csr[i + 2], e3 = csr[i + 3];
        unsigned e4 = csr[i + 4], e5 = csr[i + 5], e6 = csr[i + 6], e7 = csr[i + 7];
        float h0 = bf2f(hs16[(size_t)(e0 & 0x1FFFF) * NF1 + f]);
        float h1 = bf2f(hs16[(size_t)(e1 & 0x1FFFF) * NF1 + f]);
        float h2 = bf2f(hs16[(size_t)(e2 & 0x1FFFF) * NF1 + f]);
        float h3 = bf2f(hs16[(size_t)(e3 & 0x1FFFF) * NF1 + f]);
        float h4 = bf2f(hs16[(size_t)(e4 & 0x1FFFF) * NF1 + f]);
        float h5 = bf2f(hs16[(size_t)(e5 & 0x1FFFF) * NF1 + f]);
        float h6 = bf2f(hs16[(size_t)(e6 & 0x1FFFF) * NF1 + f]);
        float h7 = bf2f(hs16[(size_t)(e7 & 0x1FFFF) * NF1 + f]);
        acc += w15f(e0) * h0;
        acc += w15f(e1) * h1;
        acc += w15f(e2) * h2;
        acc += w15f(e3) * h3;
        acc += w15f(e4) * h4;
        acc += w15f(e5) * h5;
        acc += w15f(e6) * h6;
        acc += w15f(e7) * h7;
    }
    for (; i < e; i++) {
        unsigned e0 = csr[i];
        acc += w15f(e0) * bf2f(hs16[(size_t)(e0 & 0x1FFFF) * NF1 + f]);
    }
    x1[(size_t)node * NF1 + f] = b1[f] + di * acc;
}

// ---------- GEMM2: hh16 = bf16( dinv[j] * (relu(x1[j]) @ W2) ) ----------
__global__ __launch_bounds__(256) void gemm2_kernel(const float* __restrict__ x1,
                                                    const float* __restrict__ W2,
                                                    const float* __restrict__ dinv,
                                                    us* __restrict__ hh16, int N) {
    int j = blockIdx.x * 256 + threadIdx.x;
    if (j >= N) return;
    float xr[NF1];
#pragma unroll
    for (int f = 0; f < NF1; f++) xr[f] = fmaxf(x1[(size_t)j * NF1 + f], 0.0f);
    float d = dinv[j];
    float o[NF2];
#pragma unroll
    for (int c = 0; c < NF2; c++) {
        float acc = 0.0f;
#pragma unroll
        for (int f = 0; f < NF1; f++) acc += xr[f] * W2[f * NF2 + c];
        o[c] = d * acc;
    }
    // pack 10 bf16 as 5 uints (row offset j*20 B is 4B-aligned)
    unsigned* hp = reinterpret_cast<unsigned*>(const_cast<us*>(hh16) + (size_t)j * NF2);
#pragma unroll
    for (int cp = 0; cp < 5; cp++)
        hp[cp] = (unsigned)f2bf(o[2 * cp]) | ((unsigned)f2bf(o[2 * cp + 1]) << 16);
}

// ---------- gather layer 2 (x8 unroll) + fused log-softmax ----------
__global__ __launch_bounds__(256) void gather2_lsm_kernel(const unsigned* __restrict__ csr,
                                                          const int* __restrict__ rowptr,
                                                          const float* __restrict__ dinv,
                                                          const us* __restrict__ hh16,
                                                          const float* __restrict__ b2,
                                                          float* __restrict__ out, int N) {
    int t = blockIdx.x * 256 + threadIdx.x;
    int node = t >> 4, f = t & 15;
    bool act = (node < N) && (f < NF2);
    float acc = 0.0f;
    if (node < N) {
        int s = rowptr[node], e = rowptr[node + 1];
        float di = dinv[node];
        acc = act ? bf2f(hh16[(size_t)node * NF2 + f]) : 0.0f;   // self-loop
        int i = s;
        if (f < NF2) {
            for (; i + 7 < e; i += 8) {
                unsigned e0 = csr[i],     e1 = csr[i + 1], e2 = csr[i + 2], e3 = csr[i + 3];
                unsigned e4 = csr[i + 4], e5 = csr[i + 5], e6 = csr[i + 6], e7 = csr[i + 7];
                float h0 = bf2f(hh16[(size_t)(e0 & 0x1FFFF) * NF2 + f]);
                float h1 = bf2f(hh16[(size_t)(e1 & 0x1FFFF) * NF2 + f]);
                float h2 = bf2f(hh16[(size_t)(e2 & 0x1FFFF) * NF2 + f]);
                float h3 = bf2f(hh16[(size_t)(e3 & 0x1FFFF) * NF2 + f]);
                float h4 = bf2f(hh16[(size_t)(e4 & 0x1FFFF) * NF2 + f]);
                float h5 = bf2f(hh16[(size_t)(e5 & 0x1FFFF) * NF2 + f]);
                float h6 = bf2f(hh16[(size_t)(e6 & 0x1FFFF) * NF2 + f]);
                float h7 = bf2f(hh16[(size_t)(e7 & 0x1FFFF) * NF2 + f]);
                acc += w15f(e0) * h0;
                acc += w15f(e1) * h1;
                acc += w15f(e2) * h2;
                acc += w15f(e3) * h3;
                acc += w15f(e4) * h4;
                acc += w15f(e5) * h5;
                acc += w15f(e6) * h6;
                acc += w15f(e7) * h7;
            }
            for (; i < e; i++) {
                unsigned e0 = csr[i];
                acc += w15f(e0) * bf2f(hh16[(size_t)(e0 & 0x1FFFF) * NF2 + f]);
            }
        }
        acc = b2[f] + di * acc;  // garbage in lanes f>=10, masked below
    }
    // log-softmax across the 16-lane group (10 active lanes)
    float m = act ? acc : -INFINITY;
#pragma unroll
    for (int off = 1; off < 16; off <<= 1) m = fmaxf(m, __shfl_xor(m, off, 16));
    float p = act ? expf(acc - m) : 0.0f;
    float ssum = p;
#pragma unroll
    for (int off = 1; off < 16; off <<= 1) ssum += __shfl_xor(ssum, off, 16);
    if (act) out[(size_t)node * NF2 + f] = acc - m - logf(ssum);
}

extern "C" void kernel_launch(void* const* d_in, const int* in_sizes, int n_in,
                              void* d_out, int out_size, void* d_ws, size_t ws_size,
                              hipStream_t stream) {
    const float* x  = (const float*)d_in[0];
    const int*   ei = (const int*)d_in[1];
    const float* ew = (const float*)d_in[2];
    const float* W1 = (const float*)d_in[3];
    const float* b1 = (const float*)d_in[4];
    const float* W2 = (const float*)d_in[5];
    const float* b2 = (const float*)d_in[6];

    const int E = in_sizes[2];           // 3,200,000
    const int N = in_sizes[0] / FIN;     // 100,000
    const int* row = ei;
    const int* col = ei + E;

    const int NB   = (N + 511) >> 9;     // coarse buckets (196)
    const int NBLK = (E + EPB - 1) / EPB;

    float* out    = (float*)d_out;
    float* logits = out;                        // [N,10]
    float* x1     = out + (size_t)N * NF2;      // [N,16]

    char* ws = (char*)d_ws;
    size_t off = 0;
    auto alloc = [&](size_t bytes) { void* p = ws + off; off += (bytes + 255) / 256 * 256; return p; };
    ull*      pool    = (ull*)     alloc((size_t)E * 8);
    unsigned* csr     = (unsigned*)alloc((size_t)E * 4);          // compressed entries
    float*    part    = (float*)   alloc((size_t)SK * N * NF1 * 4);
    us*       hs16    = (us*)      alloc((size_t)N * NF1 * 2);    // bf16 dinv*(x@W1)
    us*       hh16    = (us*)      alloc((size_t)N * NF2 * 2 + 64);
    float*    dinv    = (float*)   alloc((size_t)N * 4);
    int*      rowptr  = (int*)     alloc((size_t)(N + 1) * 4);
    int*      blkhist = (int*)     alloc((size_t)NB * NBLK * 4);
    int*      btot    = (int*)     alloc((size_t)NB * 4);
    int*      bbase   = (int*)     alloc((size_t)(NB + 1) * 4);
    (void)ws_size; (void)n_in; (void)out_size;

    dim3 blk(256);
    int gN    = (N + 255) / 256;
    int g16   = (N + 15) / 16;
    int nbRow = (N + 255) / 256;         // gemm1 row-blocks per K-quarter

    // build compressed CSR (no global atomics)
    coarse_count_kernel<<<NBLK, blk, 0, stream>>>(col, blkhist, E, NB, NBLK);
    bucket_scan_kernel<<<NB, dim3(512), 0, stream>>>(blkhist, btot, NBLK);
    base_scan_kernel<<<1, blk, 0, stream>>>(btot, bbase, rowptr, NB, E, N);
    coarse_scatter_kernel<<<NBLK, blk, 0, stream>>>(row, col, ew, blkhist, bbase, pool, E, NB, NBLK);
    fine_sort_kernel<<<NB, dim3(1024), 0, stream>>>(pool, bbase, csr, rowptr, dinv, N);

    // layer 1
    gemm1_kernel<<<SK * nbRow, blk, 0, stream>>>(x, W1, part, N, nbRow);
    combine_scale_kernel<<<(N * NF1 / 4 + 255) / 256, blk, 0, stream>>>(part, dinv, hs16, N);
    gather1_kernel<<<g16, blk, 0, stream>>>(csr, rowptr, dinv, hs16, b1, x1, N);

    // layer 2
    gemm2_kernel<<<gN, blk, 0, stream>>>(x1, W2, dinv, hh16, N);
    gather2_lsm_kernel<<<g16, blk, 0, stream>>>(csr, rowptr, dinv, hh16, b2, logits, N);
}

// Round 20
// 224.809 us; speedup vs baseline: 1.3886x; 1.0154x over previous
//
#include <hip/hip_runtime.h>
#include <hip/hip_bf16.h>

// GCN 2-layer forward on MI355X — round 20 = round-19 (best, 228us) with two
// subtractive changes: (1) gemm1 split-K 4->2 (measured perf-equal in r10;
// halves the `part` round-trip, -25.6 MB); (2) gemm2 fused into gather1's
// epilogue via width-16 shuffle reductions (deletes a kernel, -6.4 MB x1
// re-read). Everything measured-good (compressed 4B CSR, x8 gather unroll,
// batched fine_sort, r8 full-line gemm1) is unchanged.
// Inputs: x[N,512] f32, edge_index[2,E] int32, edge_weight[E] f32,
//         W1[512,16], b1[16], W2[16,10], b2[10]
// Outputs (concat): log_softmax(logits)[N,10], x1[N,16]

#define NF1 16   // hidden
#define NF2 10   // classes
#define FIN 512
#define EPB 8192 // edges per coarse block (256 thr * 32)
#define SK  2    // gemm1 split-K factor

typedef unsigned long long ull;
typedef unsigned short us;

// bf16 pack/unpack (round-to-nearest-even; data has no NaN)
__device__ __forceinline__ us f2bf(float f) {
    union { float f; unsigned u; } v; v.f = f;
    unsigned r = v.u + 0x7FFFu + ((v.u >> 16) & 1u);
    return (us)(r >> 16);
}
__device__ __forceinline__ float bf2f(us h) {
    union { unsigned u; float f; } v; v.u = ((unsigned)h) << 16;
    return v.f;
}
// 15-bit positive-float weight decode: bits[30:16] stored, sign=0
__device__ __forceinline__ float w15f(unsigned e) {
    union { unsigned u; float f; } v; v.u = (e >> 17) << 16;
    return v.f;
}

// ---------- A: coarse count (col>>9) into per-block histograms ----------
__global__ __launch_bounds__(256) void coarse_count_kernel(const int* __restrict__ col,
                                                           int* __restrict__ blkhist,
                                                           int E, int NB, int NBLK) {
    __shared__ int lh[256];
    int t = threadIdx.x;
    lh[t] = 0;
    __syncthreads();
    int base = blockIdx.x * EPB;
    int cnt = min(EPB, E - base);
    for (int i = t; i < cnt; i += 256)
        atomicAdd(&lh[col[base + i] >> 9], 1);
    __syncthreads();
    if (t < NB) blkhist[t * NBLK + blockIdx.x] = lh[t];
}

// ---------- B1: per-bucket exclusive scan over blocks (parallel) ----------
__global__ __launch_bounds__(512) void bucket_scan_kernel(int* __restrict__ blkhist,
                                                          int* __restrict__ btot,
                                                          int NBLK) {
    __shared__ int s[512];
    int t = threadIdx.x;
    int* p = blkhist + (size_t)blockIdx.x * NBLK;
    int carry = 0;
    for (int base = 0; base < NBLK; base += 512) {
        int idx = base + t;
        int v = (idx < NBLK) ? p[idx] : 0;
        s[t] = v;
        __syncthreads();
        for (int off = 1; off < 512; off <<= 1) {
            int u = (t >= off) ? s[t - off] : 0;
            __syncthreads();
            s[t] += u;
            __syncthreads();
        }
        if (idx < NBLK) p[idx] = s[t] - v + carry;
        carry += s[511];
        __syncthreads();
    }
    if (t == 0) btot[blockIdx.x] = carry;
}

// ---------- B2: scan bucket totals -> bbase ----------
__global__ __launch_bounds__(256) void base_scan_kernel(const int* __restrict__ btot,
                                                        int* __restrict__ bbase,
                                                        int* __restrict__ rowptr,
                                                        int NB, int E, int N) {
    __shared__ int s[256];
    int t = threadIdx.x;
    int v = (t < NB) ? btot[t] : 0;
    s[t] = v;
    __syncthreads();
    for (int off = 1; off < 256; off <<= 1) {
        int u = (t >= off) ? s[t - off] : 0;
        __syncthreads();
        s[t] += u;
        __syncthreads();
    }
    if (t < NB) bbase[t] = s[t] - v;
    if (t == 0) { bbase[NB] = E; rowptr[N] = E; }
}

// ---------- C: coarse scatter into bucket-ordered pool ----------
// pool entry: hi32 = (c9<<20)|row, lo32 = weight bits (f32)
__global__ __launch_bounds__(256) void coarse_scatter_kernel(const int* __restrict__ row,
                                                             const int* __restrict__ col,
                                                             const float* __restrict__ ew,
                                                             const int* __restrict__ blkhist,
                                                             const int* __restrict__ bbase,
                                                             ull* __restrict__ pool,
                                                             int E, int NB, int NBLK) {
    __shared__ int cur[256];
    int t = threadIdx.x;
    if (t < NB) cur[t] = blkhist[t * NBLK + blockIdx.x] + bbase[t];
    __syncthreads();
    int base = blockIdx.x * EPB;
    int cnt = min(EPB, E - base);
    for (int i = t; i < cnt; i += 256) {
        int e = base + i;
        int c = col[e], r = row[e];
        float w = ew[e];
        int b = c >> 9, c9 = c & 511;
        int pos = atomicAdd(&cur[b], 1);
        pool[pos] = ((ull)((((unsigned)c9) << 20) | (unsigned)r) << 32) | (ull)__float_as_uint(w);
    }
}

// ---------- D: fine sort within bucket -> compressed CSR, rowptr, dinv ----------
__global__ __launch_bounds__(1024) void fine_sort_kernel(const ull* __restrict__ pool,
                                                         const int* __restrict__ bbase,
                                                         unsigned* __restrict__ csr,
                                                         int* __restrict__ rowptr,
                                                         float* __restrict__ dinv, int N) {
    __shared__ int hist[512];
    __shared__ float wsum[512];
    __shared__ int cur[512];
    int t = threadIdx.x;
    int b = blockIdx.x;
    int bb = bbase[b], be = bbase[b + 1];
    int Ki = be - bb;
    if (t < 512) { hist[t] = 0; wsum[t] = 0.0f; }
    __syncthreads();
    // pass 1: hist + wsum, x4-batched loads
    int i = t;
    for (; i + 3 * 1024 < Ki; i += 4 * 1024) {
        ull p0 = pool[bb + i];
        ull p1 = pool[bb + i + 1024];
        ull p2 = pool[bb + i + 2048];
        ull p3 = pool[bb + i + 3072];
        unsigned h0 = (unsigned)(p0 >> 32), h1 = (unsigned)(p1 >> 32);
        unsigned h2 = (unsigned)(p2 >> 32), h3 = (unsigned)(p3 >> 32);
        atomicAdd(&hist[(h0 >> 20) & 511], 1);
        atomicAdd(&wsum[(h0 >> 20) & 511], __uint_as_float((unsigned)p0));
        atomicAdd(&hist[(h1 >> 20) & 511], 1);
        atomicAdd(&wsum[(h1 >> 20) & 511], __uint_as_float((unsigned)p1));
        atomicAdd(&hist[(h2 >> 20) & 511], 1);
        atomicAdd(&wsum[(h2 >> 20) & 511], __uint_as_float((unsigned)p2));
        atomicAdd(&hist[(h3 >> 20) & 511], 1);
        atomicAdd(&wsum[(h3 >> 20) & 511], __uint_as_float((unsigned)p3));
    }
    for (; i < Ki; i += 1024) {
        ull p = pool[bb + i];
        unsigned hi = (unsigned)(p >> 32);
        int c9 = (hi >> 20) & 511;
        atomicAdd(&hist[c9], 1);
        atomicAdd(&wsum[c9], __uint_as_float((unsigned)p));
    }
    __syncthreads();
    int own = (t < 512) ? hist[t] : 0;
    if (t < 512) cur[t] = own;
    __syncthreads();
    for (int off = 1; off < 512; off <<= 1) {
        int v = (t >= off && t < 512) ? cur[t - off] : 0;
        __syncthreads();
        if (t < 512) cur[t] += v;
        __syncthreads();
    }
    int excl = (t < 512) ? (cur[t] - own) : 0;
    if (t < 512) cur[t] = excl;
    int c = (b << 9) + t;
    if (t < 512 && c < N) {
        rowptr[c] = bb + excl;
        dinv[c] = rsqrtf(1.0f + wsum[t]);       // deg = self(1) + sum(w)
    }
    __syncthreads();
    // pass 2: place, x4-batched loads
    i = t;
    for (; i + 3 * 1024 < Ki; i += 4 * 1024) {
        ull p0 = pool[bb + i];
        ull p1 = pool[bb + i + 1024];
        ull p2 = pool[bb + i + 2048];
        ull p3 = pool[bb + i + 3072];
#pragma unroll
        for (int j = 0; j < 4; j++) {
            ull p = (j == 0) ? p0 : (j == 1) ? p1 : (j == 2) ? p2 : p3;
            unsigned hi = (unsigned)(p >> 32);
            int c9 = (hi >> 20) & 511;
            unsigned r = hi & 0xFFFFFu;
            unsigned lo = (unsigned)p;
            unsigned w15 = (lo + 0x8000u) >> 16;
            int k = atomicAdd(&cur[c9], 1);
            csr[bb + k] = (w15 << 17) | r;
        }
    }
    for (; i < Ki; i += 1024) {
        ull p = pool[bb + i];
        unsigned hi = (unsigned)(p >> 32);
        int c9 = (hi >> 20) & 511;
        unsigned r = hi & 0xFFFFFu;
        unsigned lo = (unsigned)p;
        unsigned w15 = (lo + 0x8000u) >> 16;
        int k = atomicAdd(&cur[c9], 1);
        csr[bb + k] = (w15 << 17) | r;
    }
}

// ---------- GEMM1 (split-K=2, no LDS, full-line loads): part[q][row][f] ----------
__device__ __forceinline__ void fma16(float av, const float* __restrict__ wrow,
                                      float* __restrict__ acc) {
#pragma unroll
    for (int f = 0; f < NF1; f++) acc[f] = fmaf(av, wrow[f], acc[f]);
}

__global__ __launch_bounds__(256) void gemm1_kernel(const float* __restrict__ x,
                                                    const float* __restrict__ W1,
                                                    float* __restrict__ part,
                                                    int N, int nbRow) {
    int b = blockIdx.x;
    int q = (b >= nbRow) ? 1 : 0;      // K-half
    int rb = b - q * nbRow;
    int row = rb * 256 + threadIdx.x;
    if (row >= N) return;
    const int k0 = q * (FIN / SK);     // 256 per half

    float acc[NF1];
#pragma unroll
    for (int f = 0; f < NF1; f++) acc[f] = 0.0f;

    const float* xr = x + (size_t)row * FIN + k0;
    const float* wp = W1 + (size_t)k0 * NF1;

#pragma unroll 2
    for (int k = 0; k < FIN / SK; k += 16) {
        const float4* xp = reinterpret_cast<const float4*>(xr + k);
        float4 a0 = xp[0];
        float4 a1 = xp[1];
        float4 a2 = xp[2];
        float4 a3 = xp[3];
        const float* wk = wp + (size_t)k * NF1;
        fma16(a0.x, wk + 0 * NF1, acc);
        fma16(a0.y, wk + 1 * NF1, acc);
        fma16(a0.z, wk + 2 * NF1, acc);
        fma16(a0.w, wk + 3 * NF1, acc);
        fma16(a1.x, wk + 4 * NF1, acc);
        fma16(a1.y, wk + 5 * NF1, acc);
        fma16(a1.z, wk + 6 * NF1, acc);
        fma16(a1.w, wk + 7 * NF1, acc);
        fma16(a2.x, wk + 8 * NF1, acc);
        fma16(a2.y, wk + 9 * NF1, acc);
        fma16(a2.z, wk + 10 * NF1, acc);
        fma16(a2.w, wk + 11 * NF1, acc);
        fma16(a3.x, wk + 12 * NF1, acc);
        fma16(a3.y, wk + 13 * NF1, acc);
        fma16(a3.z, wk + 14 * NF1, acc);
        fma16(a3.w, wk + 15 * NF1, acc);
    }

    float* pp = part + ((size_t)q * N + row) * NF1;
#pragma unroll
    for (int qq = 0; qq < 4; qq++) {
        float4 o = make_float4(acc[4 * qq], acc[4 * qq + 1], acc[4 * qq + 2], acc[4 * qq + 3]);
        *reinterpret_cast<float4*>(pp + 4 * qq) = o;
    }
}

// ---------- combine split-K partials, fold dinv, pack bf16: hs16 = bf16(dinv*(Σp)) ----------
__global__ __launch_bounds__(256) void combine_scale_kernel(const float* __restrict__ part,
                                                            const float* __restrict__ dinv,
                                                            us* __restrict__ hs16, int N) {
    int i4 = blockIdx.x * 256 + threadIdx.x;     // 4-float chunk index
    int total = N * NF1 / 4;
    if (i4 >= total) return;
    int rowIdx = i4 >> 2;                        // 4 chunks per row
    const float4* p0 = reinterpret_cast<const float4*>(part);
    const float4* p1 = reinterpret_cast<const float4*>(part + (size_t)N * NF1);
    float4 a = p0[i4], b = p1[i4];
    float d = dinv[rowIdx];
    ushort4 u;
    u.x = f2bf(d * (a.x + b.x));
    u.y = f2bf(d * (a.y + b.y));
    u.z = f2bf(d * (a.z + b.z));
    u.w = f2bf(d * (a.w + b.w));
    reinterpret_cast<ushort4*>(hs16)[i4] = u;
}

// ---------- gather layer 1 (x8 unroll) + FUSED gemm2 ----------
// x1[c] = b1 + di*( sum w_i*hs[r_i] + hs[c] );  hh = bf16(di * relu(x1)@W2)
__global__ __launch_bounds__(256) void gather1_gemm2_kernel(const unsigned* __restrict__ csr,
                                                            const int* __restrict__ rowptr,
                                                            const float* __restrict__ dinv,
                                                            const us* __restrict__ hs16,
                                                            const float* __restrict__ b1,
                                                            const float* __restrict__ W2,
                                                            float* __restrict__ x1,
                                                            us* __restrict__ hh16, int N) {
    int t = blockIdx.x * 256 + threadIdx.x;
    int node = t >> 4, f = t & 15;
    if (node >= N) return;
    int s = rowptr[node], e = rowptr[node + 1];
    float di = dinv[node];
    float acc = bf2f(hs16[(size_t)node * NF1 + f]);   // self-loop: hs[c]
    int i = s;
    for (; i + 7 < e; i += 8) {
        unsigned e0 = csr[i],     e1 = csr[i + 1], e2 = csr[i + 2], e3 = csr[i + 3];
        unsigned e4 = csr[i + 4], e5 = csr[i + 5], e6 = csr[i + 6], e7 = csr[i + 7];
        float h0 = bf2f(hs16[(size_t)(e0 & 0x1FFFF) * NF1 + f]);
        float h1 = bf2f(hs16[(size_t)(e1 & 0x1FFFF) * NF1 + f]);
        float h2 = bf2f(hs16[(size_t)(e2 & 0x1FFFF) * NF1 + f]);
        float h3 = bf2f(hs16[(size_t)(e3 & 0x1FFFF) * NF1 + f]);
        float h4 = bf2f(hs16[(size_t)(e4 & 0x1FFFF) * NF1 + f]);
        float h5 = bf2f(hs16[(size_t)(e5 & 0x1FFFF) * NF1 + f]);
        float h6 = bf2f(hs16[(size_t)(e6 & 0x1FFFF) * NF1 + f]);
        float h7 = bf2f(hs16[(size_t)(e7 & 0x1FFFF) * NF1 + f]);
        acc += w15f(e0) * h0;
        acc += w15f(e1) * h1;
        acc += w15f(e2) * h2;
        acc += w15f(e3) * h3;
        acc += w15f(e4) * h4;
        acc += w15f(e5) * h5;
        acc += w15f(e6) * h6;
        acc += w15f(e7) * h7;
    }
    for (; i < e; i++) {
        unsigned e0 = csr[i];
        acc += w15f(e0) * bf2f(hs16[(size_t)(e0 & 0x1FFFF) * NF1 + f]);
    }
    float x1v = b1[f] + di * acc;
    x1[(size_t)node * NF1 + f] = x1v;

    // fused gemm2: each 16-lane group holds the full x1 row
    float xr = fmaxf(x1v, 0.0f);
    float hhv = 0.0f;
#pragma unroll
    for (int c = 0; c < NF2; c++) {
        float v = xr * W2[f * NF2 + c];
#pragma unroll
        for (int off = 1; off < 16; off <<= 1) v += __shfl_xor(v, off, 16);
        if (f == c) hhv = v;
    }
    if (f < NF2) hh16[(size_t)node * NF2 + f] = f2bf(di * hhv);
}

// ---------- gather layer 2 (x8 unroll) + fused log-softmax ----------
__global__ __launch_bounds__(256) void gather2_lsm_kernel(const unsigned* __restrict__ csr,
                                                          const int* __restrict__ rowptr,
                                                          const float* __restrict__ dinv,
                                                          const us* __restrict__ hh16,
                                                          const float* __restrict__ b2,
                                                          float* __restrict__ out, int N) {
    int t = blockIdx.x * 256 + threadIdx.x;
    int node = t >> 4, f = t & 15;
    bool act = (node < N) && (f < NF2);
    float acc = 0.0f;
    if (node < N) {
        int s = rowptr[node], e = rowptr[node + 1];
        float di = dinv[node];
        acc = act ? bf2f(hh16[(size_t)node * NF2 + f]) : 0.0f;   // self-loop
        int i = s;
        if (f < NF2) {
            for (; i + 7 < e; i += 8) {
                unsigned e0 = csr[i],     e1 = csr[i + 1], e2 = csr[i + 2], e3 = csr[i + 3];
                unsigned e4 = csr[i + 4], e5 = csr[i + 5], e6 = csr[i + 6], e7 = csr[i + 7];
                float h0 = bf2f(hh16[(size_t)(e0 & 0x1FFFF) * NF2 + f]);
                float h1 = bf2f(hh16[(size_t)(e1 & 0x1FFFF) * NF2 + f]);
                float h2 = bf2f(hh16[(size_t)(e2 & 0x1FFFF) * NF2 + f]);
                float h3 = bf2f(hh16[(size_t)(e3 & 0x1FFFF) * NF2 + f]);
                float h4 = bf2f(hh16[(size_t)(e4 & 0x1FFFF) * NF2 + f]);
                float h5 = bf2f(hh16[(size_t)(e5 & 0x1FFFF) * NF2 + f]);
                float h6 = bf2f(hh16[(size_t)(e6 & 0x1FFFF) * NF2 + f]);
                float h7 = bf2f(hh16[(size_t)(e7 & 0x1FFFF) * NF2 + f]);
                acc += w15f(e0) * h0;
                acc += w15f(e1) * h1;
                acc += w15f(e2) * h2;
                acc += w15f(e3) * h3;
                acc += w15f(e4) * h4;
                acc += w15f(e5) * h5;
                acc += w15f(e6) * h6;
                acc += w15f(e7) * h7;
            }
            for (; i < e; i++) {
                unsigned e0 = csr[i];
                acc += w15f(e0) * bf2f(hh16[(size_t)(e0 & 0x1FFFF) * NF2 + f]);
            }
        }
        acc = b2[f] + di * acc;  // garbage in lanes f>=10, masked below
    }
    // log-softmax across the 16-lane group (10 active lanes)
    float m = act ? acc : -INFINITY;
#pragma unroll
    for (int off = 1; off < 16; off <<= 1) m = fmaxf(m, __shfl_xor(m, off, 16));
    float p = act ? expf(acc - m) : 0.0f;
    float ssum = p;
#pragma unroll
    for (int off = 1; off < 16; off <<= 1) ssum += __shfl_xor(ssum, off, 16);
    if (act) out[(size_t)node * NF2 + f] = acc - m - logf(ssum);
}

extern "C" void kernel_launch(void* const* d_in, const int* in_sizes, int n_in,
                              void* d_out, int out_size, void* d_ws, size_t ws_size,
                              hipStream_t stream) {
    const float* x  = (const float*)d_in[0];
    const int*   ei = (const int*)d_in[1];
    const float* ew = (const float*)d_in[2];
    const float* W1 = (const float*)d_in[3];
    const float* b1 = (const float*)d_in[4];
    const float* W2 = (const float*)d_in[5];
    const float* b2 = (const float*)d_in[6];

    const int E = in_sizes[2];           // 3,200,000
    const int N = in_sizes[0] / FIN;     // 100,000
    const int* row = ei;
    const int* col = ei + E;

    const int NB   = (N + 511) >> 9;     // coarse buckets (196)
    const int NBLK = (E + EPB - 1) / EPB;

    float* out    = (float*)d_out;
    float* logits = out;                        // [N,10]
    float* x1     = out + (size_t)N * NF2;      // [N,16]

    char* ws = (char*)d_ws;
    size_t off = 0;
    auto alloc = [&](size_t bytes) { void* p = ws + off; off += (bytes + 255) / 256 * 256; return p; };
    ull*      pool    = (ull*)     alloc((size_t)E * 8);
    unsigned* csr     = (unsigned*)alloc((size_t)E * 4);          // compressed entries
    float*    part    = (float*)   alloc((size_t)SK * N * NF1 * 4);
    us*       hs16    = (us*)      alloc((size_t)N * NF1 * 2);    // bf16 dinv*(x@W1)
    us*       hh16    = (us*)      alloc((size_t)N * NF2 * 2 + 64);
    float*    dinv    = (float*)   alloc((size_t)N * 4);
    int*      rowptr  = (int*)     alloc((size_t)(N + 1) * 4);
    int*      blkhist = (int*)     alloc((size_t)NB * NBLK * 4);
    int*      btot    = (int*)     alloc((size_t)NB * 4);
    int*      bbase   = (int*)     alloc((size_t)(NB + 1) * 4);
    (void)ws_size; (void)n_in; (void)out_size;

    dim3 blk(256);
    int g16   = (N + 15) / 16;
    int nbRow = (N + 255) / 256;         // gemm1 row-blocks per K-half

    // build compressed CSR (no global atomics)
    coarse_count_kernel<<<NBLK, blk, 0, stream>>>(col, blkhist, E, NB, NBLK);
    bucket_scan_kernel<<<NB, dim3(512), 0, stream>>>(blkhist, btot, NBLK);
    base_scan_kernel<<<1, blk, 0, stream>>>(btot, bbase, rowptr, NB, E, N);
    coarse_scatter_kernel<<<NBLK, blk, 0, stream>>>(row, col, ew, blkhist, bbase, pool, E, NB, NBLK);
    fine_sort_kernel<<<NB, dim3(1024), 0, stream>>>(pool, bbase, csr, rowptr, dinv, N);

    // layer 1 (+ fused layer-2 GEMM)
    gemm1_kernel<<<SK * nbRow, blk, 0, stream>>>(x, W1, part, N, nbRow);
    combine_scale_kernel<<<(N * NF1 / 4 + 255) / 256, blk, 0, stream>>>(part, dinv, hs16, N);
    gather1_gemm2_kernel<<<g16, blk, 0, stream>>>(csr, rowptr, dinv, hs16, b1, W2, x1, hh16, N);

    // layer 2 aggregation + log-softmax
    gather2_lsm_kernel<<<g16, blk, 0, stream>>>(csr, rowptr, dinv, hh16, b2, logits, N);
}